// Round 1
// baseline (678.345 us; speedup 1.0000x reference)
//
#include <hip/hip_runtime.h>
#include <hip/hip_bf16.h>

using short8 = __attribute__((ext_vector_type(8))) short;
using f32x4  = __attribute__((ext_vector_type(4))) float;

#define SEQ 2048
#define NHEAD 32
#define NKVH 4
#define HDIM 128
#define QK_SCALE 0.08838834764831845f

// ---------------------------------------------------------------- cast fp32 -> bf16
__global__ void cast_bf16_kernel(const float* __restrict__ in, __hip_bfloat16* __restrict__ out, int n4) {
    int i = blockIdx.x * blockDim.x + threadIdx.x;
    if (i >= n4) return;
    float4 v = ((const float4*)in)[i];
    __hip_bfloat16 h[4] = {__float2bfloat16(v.x), __float2bfloat16(v.y),
                           __float2bfloat16(v.z), __float2bfloat16(v.w)};
    ((ushort4*)out)[i] = *(ushort4*)h;
}

// ---------------------------------------------------------------- transpose + cast: W (K,N) fp32 -> Wt (N,K) bf16
__global__ __launch_bounds__(256) void transpose_cast_kernel(
    const float* __restrict__ W, __hip_bfloat16* __restrict__ Wt, int K, int N) {
    __shared__ float tile[32][33];
    int tx = threadIdx.x & 31, ty = threadIdx.x >> 5;   // 32 x 8
    int nb = blockIdx.x * 32, kb = blockIdx.y * 32;
    for (int j = 0; j < 32; j += 8)
        tile[ty + j][tx] = W[(size_t)(kb + ty + j) * N + nb + tx];
    __syncthreads();
    for (int j = 0; j < 32; j += 8)
        Wt[(size_t)(nb + ty + j) * K + kb + tx] = __float2bfloat16(tile[tx][ty + j]);
}

// ---------------------------------------------------------------- GEMM: A(M,K)bf16 x Bt(N,K)bf16 -> C(M,N)fp32
#define BM 128
#define BN 128
#define BKK 32
__global__ __launch_bounds__(256) void gemm_bt_kernel(
    const __hip_bfloat16* __restrict__ A, const __hip_bfloat16* __restrict__ Bt,
    float* __restrict__ C, int M, int N, int K) {
    __shared__ __align__(16) __hip_bfloat16 sA[BM * BKK];
    __shared__ __align__(16) __hip_bfloat16 sB[BN * BKK];
    const int tid = threadIdx.x;
    const int w = tid >> 6, l = tid & 63;
    const int wr = w >> 1, wc = w & 1;
    const int row0 = blockIdx.y * BM;
    const int col0 = blockIdx.x * BN;
    const int srow = l >> 2;          // 0..15
    const int scol = (l & 3) * 8;     // 0,8,16,24

    f32x4 acc[4][4] = {};
    const int fr = l & 15;
    const int fc = (l >> 4) * 8;

    for (int k0 = 0; k0 < K; k0 += BKK) {
        for (int i = 0; i < 2; ++i) {
            int c = i * 4 + w;  // chunk 0..7, 16 rows each
            const __hip_bfloat16* ga = A + (size_t)(row0 + c * 16 + srow) * K + k0 + scol;
            __builtin_amdgcn_global_load_lds((const __attribute__((address_space(1))) void*)ga,
                                             (__attribute__((address_space(3))) void*)&sA[c * 16 * BKK], 16, 0, 0);
            const __hip_bfloat16* gb = Bt + (size_t)(col0 + c * 16 + srow) * K + k0 + scol;
            __builtin_amdgcn_global_load_lds((const __attribute__((address_space(1))) void*)gb,
                                             (__attribute__((address_space(3))) void*)&sB[c * 16 * BKK], 16, 0, 0);
        }
        __syncthreads();
        short8 af[4], bfr[4];
        for (int m = 0; m < 4; ++m)
            af[m] = *(const short8*)&sA[(wr * 64 + m * 16 + fr) * BKK + fc];
        for (int n = 0; n < 4; ++n)
            bfr[n] = *(const short8*)&sB[(wc * 64 + n * 16 + fr) * BKK + fc];
        for (int m = 0; m < 4; ++m)
            for (int n = 0; n < 4; ++n)
                acc[m][n] = __builtin_amdgcn_mfma_f32_16x16x32_bf16(af[m], bfr[n], acc[m][n], 0, 0, 0);
        __syncthreads();
    }
    const int fq = l >> 4;
    for (int m = 0; m < 4; ++m)
        for (int n = 0; n < 4; ++n)
            for (int r = 0; r < 4; ++r) {
                int row = row0 + wr * 64 + m * 16 + fq * 4 + r;
                int col = col0 + wc * 64 + n * 16 + fr;
                C[(size_t)row * N + col] = acc[m][n][r];
            }
}

// ---------------------------------------------------------------- fused RMSNorm + RoPE + pack
__global__ __launch_bounds__(256) void pack_kernel(
    const float* __restrict__ QKV, const float* __restrict__ cosp, const float* __restrict__ sinp,
    const float* __restrict__ qnw, const float* __restrict__ knw,
    __hip_bfloat16* __restrict__ Qh, __hip_bfloat16* __restrict__ Kh, __hip_bfloat16* __restrict__ Vt) {
    const int s = blockIdx.x;
    const int slot = blockIdx.y * 4 + (threadIdx.x >> 6);  // 0..39
    const int d = threadIdx.x & 63;
    const float* row = QKV + (size_t)s * 5120;
    float x1, x2;
    if (slot < 32)      { x1 = row[slot * 128 + d];              x2 = row[slot * 128 + d + 64]; }
    else if (slot < 36) { int t = slot - 32; x1 = row[4096 + t * 128 + d]; x2 = row[4096 + t * 128 + d + 64]; }
    else                { int t = slot - 36; x1 = row[4608 + t * 128 + d]; x2 = row[4608 + t * 128 + d + 64]; }

    if (slot >= 36) {   // V: just cast + transpose to (D,S)
        int t = slot - 36;
        Vt[((size_t)t * 128 + d) * SEQ + s]      = __float2bfloat16(x1);
        Vt[((size_t)t * 128 + d + 64) * SEQ + s] = __float2bfloat16(x2);
        return;
    }
    float ss = x1 * x1 + x2 * x2;
    for (int x = 1; x < 64; x <<= 1) ss += __shfl_xor(ss, x);
    float rs = rsqrtf(ss * (1.0f / 128.0f) + 1e-6f);
    float c = cosp[s * 128 + d], sn = sinp[s * 128 + d];  // cos[d]==cos[d+64]
    if (slot < 32) {
        float a = x1 * rs * qnw[d], b = x2 * rs * qnw[d + 64];
        float o1 = (a * c - b * sn) * QK_SCALE;
        float o2 = (b * c + a * sn) * QK_SCALE;
        Qh[((size_t)slot * SEQ + s) * 128 + d]      = __float2bfloat16(o1);
        Qh[((size_t)slot * SEQ + s) * 128 + d + 64] = __float2bfloat16(o2);
    } else {
        int t = slot - 32;
        float a = x1 * rs * knw[d], b = x2 * rs * knw[d + 64];
        float o1 = a * c - b * sn;
        float o2 = b * c + a * sn;
        Kh[((size_t)t * SEQ + s) * 128 + d]      = __float2bfloat16(o1);
        Kh[((size_t)t * SEQ + s) * 128 + d + 64] = __float2bfloat16(o2);
    }
}

// ---------------------------------------------------------------- causal GQA flash attention
__global__ __launch_bounds__(256) void attn_kernel(
    const __hip_bfloat16* __restrict__ Qh,  // [NH][S][D], scale folded
    const __hip_bfloat16* __restrict__ Kh,  // [NKV][S][D]
    const __hip_bfloat16* __restrict__ Vt,  // [NKV][D][S]
    __hip_bfloat16* __restrict__ Oa) {      // [S][NH*D]
    __shared__ __align__(16) __hip_bfloat16 sP[4][16 * 40];  // per-wave 16x32 P (pad to 40)
    const int tid = threadIdx.x;
    const int w = tid >> 6, l = tid & 63;
    const int h = blockIdx.y;
    const int hkv = h >> 3;
    const int qbase = blockIdx.x * 64 + w * 16;
    const int fr = l & 15, g = l >> 4;
    const __hip_bfloat16* Qp = Qh + ((size_t)h * SEQ + qbase) * HDIM;
    const __hip_bfloat16* Kp = Kh + (size_t)hkv * SEQ * HDIM;
    const __hip_bfloat16* Vp = Vt + (size_t)hkv * HDIM * SEQ;
    __hip_bfloat16* myP = &sP[w][0];

    short8 qf[4];
    for (int c = 0; c < 4; ++c)
        qf[c] = *(const short8*)&Qp[fr * HDIM + c * 32 + g * 8];

    f32x4 oacc[8] = {};
    float mrow[4], lrow[4];
    for (int r = 0; r < 4; ++r) { mrow[r] = -3.0e38f; lrow[r] = 0.f; }

    const int ntiles = ((qbase + 15) >> 5) + 1;
    for (int t = 0; t < ntiles; ++t) {
        const int kbase = t * 32;
        f32x4 s0 = {}, s1 = {};
        for (int c = 0; c < 4; ++c) {
            short8 kf0 = *(const short8*)&Kp[(size_t)(kbase + fr) * HDIM + c * 32 + g * 8];
            short8 kf1 = *(const short8*)&Kp[(size_t)(kbase + 16 + fr) * HDIM + c * 32 + g * 8];
            s0 = __builtin_amdgcn_mfma_f32_16x16x32_bf16(qf[c], kf0, s0, 0, 0, 0);
            s1 = __builtin_amdgcn_mfma_f32_16x16x32_bf16(qf[c], kf1, s1, 0, 0, 0);
        }
        float corr[4];
        for (int r = 0; r < 4; ++r) {
            int qg = qbase + g * 4 + r;
            float v0 = (kbase + fr      <= qg) ? s0[r] : -1e30f;
            float v1 = (kbase + 16 + fr <= qg) ? s1[r] : -1e30f;
            float m = fmaxf(v0, v1);
            for (int x = 1; x < 16; x <<= 1) m = fmaxf(m, __shfl_xor(m, x));
            float mnew = fmaxf(mrow[r], m);
            corr[r] = __expf(mrow[r] - mnew);
            mrow[r] = mnew;
            float p0 = __expf(v0 - mnew);
            float p1 = __expf(v1 - mnew);
            float sum = p0 + p1;
            for (int x = 1; x < 16; x <<= 1) sum += __shfl_xor(sum, x);
            lrow[r] = lrow[r] * corr[r] + sum;
            myP[(g * 4 + r) * 40 + fr]      = __float2bfloat16(p0);
            myP[(g * 4 + r) * 40 + 16 + fr] = __float2bfloat16(p1);
        }
        for (int dt = 0; dt < 8; ++dt)
            for (int r = 0; r < 4; ++r) oacc[dt][r] *= corr[r];
        short8 pa = *(const short8*)&myP[fr * 40 + g * 8];
        for (int dt = 0; dt < 8; ++dt) {
            short8 vb = *(const short8*)&Vp[(size_t)(dt * 16 + fr) * SEQ + kbase + g * 8];
            oacc[dt] = __builtin_amdgcn_mfma_f32_16x16x32_bf16(pa, vb, oacc[dt], 0, 0, 0);
        }
    }
    for (int r = 0; r < 4; ++r) lrow[r] = 1.0f / lrow[r];
    for (int dt = 0; dt < 8; ++dt)
        for (int r = 0; r < 4; ++r) {
            int qg = qbase + g * 4 + r;
            Oa[(size_t)qg * (NHEAD * HDIM) + h * HDIM + dt * 16 + fr] =
                __float2bfloat16(oacc[dt][r] * lrow[r]);
        }
}

// ---------------------------------------------------------------- launch
extern "C" void kernel_launch(void* const* d_in, const int* in_sizes, int n_in,
                              void* d_out, int out_size, void* d_ws, size_t ws_size,
                              hipStream_t stream) {
    const float* hs   = (const float*)d_in[0];
    const float* cosp = (const float*)d_in[1];
    const float* sinp = (const float*)d_in[2];
    const float* wq   = (const float*)d_in[3];
    const float* wk   = (const float*)d_in[4];
    const float* wv   = (const float*)d_in[5];
    const float* wo   = (const float*)d_in[6];
    const float* qnw  = (const float*)d_in[7];
    const float* knw  = (const float*)d_in[8];
    float* out = (float*)d_out;
    char* ws = (char*)d_ws;

    // workspace layout (aliased stages)
    __hip_bfloat16* hsb    = (__hip_bfloat16*)(ws);                         // 8,388,608 B
    __hip_bfloat16* WqkvT  = (__hip_bfloat16*)(ws + 8388608);               // 20,971,520 B (5120x2048)
    __hip_bfloat16* WoT    = (__hip_bfloat16*)(ws + 29360128);              // 16,777,216 B (2048x4096)
    float*          QKV    = (float*)(ws + 46137344);                       // 41,943,040 B (2048x5120)
    // after QKV GEMM, WqkvT region is reused for packed Q/K/V:
    __hip_bfloat16* Qh     = (__hip_bfloat16*)(ws + 8388608);               // 16,777,216 B
    __hip_bfloat16* Kh     = (__hip_bfloat16*)(ws + 8388608 + 16777216);    //  2,097,152 B
    __hip_bfloat16* Vt     = (__hip_bfloat16*)(ws + 8388608 + 18874368);    //  2,097,152 B
    // after pack, QKV region is reused for attention output:
    __hip_bfloat16* Oa     = (__hip_bfloat16*)(ws + 46137344);              // 16,777,216 B

    cast_bf16_kernel<<<4096, 256, 0, stream>>>(hs, hsb, (SEQ * 2048) / 4);
    transpose_cast_kernel<<<dim3(128, 64), 256, 0, stream>>>(wq, WqkvT, 2048, 4096);
    transpose_cast_kernel<<<dim3(16, 64), 256, 0, stream>>>(wk, WqkvT + (size_t)4096 * 2048, 2048, 512);
    transpose_cast_kernel<<<dim3(16, 64), 256, 0, stream>>>(wv, WqkvT + (size_t)4608 * 2048, 2048, 512);
    transpose_cast_kernel<<<dim3(64, 128), 256, 0, stream>>>(wo, WoT, 4096, 2048);

    gemm_bt_kernel<<<dim3(40, 16), 256, 0, stream>>>(hsb, WqkvT, QKV, 2048, 5120, 2048);
    pack_kernel<<<dim3(2048, 10), 256, 0, stream>>>(QKV, cosp, sinp, qnw, knw, Qh, Kh, Vt);
    attn_kernel<<<dim3(32, 32), 256, 0, stream>>>(Qh, Kh, Vt, Oa);
    gemm_bt_kernel<<<dim3(16, 16), 256, 0, stream>>>(Oa, WoT, out, 2048, 2048, 4096);
}

// Round 3
// 656.172 us; speedup vs baseline: 1.0338x; 1.0338x over previous
//
#include <hip/hip_runtime.h>
#include <hip/hip_bf16.h>

using short8 = __attribute__((ext_vector_type(8))) short;
using f32x4  = __attribute__((ext_vector_type(4))) float;

#define SEQ 2048
#define NHEAD 32
#define NKVH 4
#define HDIM 128
// 1/sqrt(128) * log2(e)  -- exp2-domain softmax, folded into Q at pack time
#define QK_SCALE_LOG2 (0.08838834764831845f * 1.44269504088896340f)

__device__ __forceinline__ float fast_exp2(float x) { return __builtin_amdgcn_exp2f(x); }

// ---------------------------------------------------------------- cast fp32 -> bf16
__global__ void cast_bf16_kernel(const float* __restrict__ in, __hip_bfloat16* __restrict__ out, int n4) {
    int i = blockIdx.x * blockDim.x + threadIdx.x;
    if (i >= n4) return;
    float4 v = ((const float4*)in)[i];
    __hip_bfloat16 h[4] = {__float2bfloat16(v.x), __float2bfloat16(v.y),
                           __float2bfloat16(v.z), __float2bfloat16(v.w)};
    ((ushort4*)out)[i] = *(ushort4*)h;
}

// ---------------------------------------------------------------- transpose + cast: W (K,N) fp32 -> Wt (N,K) bf16
__global__ __launch_bounds__(256) void transpose_cast_kernel(
    const float* __restrict__ W, __hip_bfloat16* __restrict__ Wt, int K, int N) {
    __shared__ float tile[32][33];
    int tx = threadIdx.x & 31, ty = threadIdx.x >> 5;   // 32 x 8
    int nb = blockIdx.x * 32, kb = blockIdx.y * 32;
    for (int j = 0; j < 32; j += 8)
        tile[ty + j][tx] = W[(size_t)(kb + ty + j) * N + nb + tx];
    __syncthreads();
    for (int j = 0; j < 32; j += 8)
        Wt[(size_t)(nb + ty + j) * K + kb + tx] = __float2bfloat16(tile[tx][ty + j]);
}

// ---------------------------------------------------------------- GEMM: A(M,K)bf16 x Bt(N,K)bf16 -> C(M,N)fp32
#define BM 128
#define BN 128
#define BKK 32
__global__ __launch_bounds__(256) void gemm_bt_kernel(
    const __hip_bfloat16* __restrict__ A, const __hip_bfloat16* __restrict__ Bt,
    float* __restrict__ C, int M, int N, int K) {
    __shared__ __align__(16) __hip_bfloat16 sA[BM * BKK];
    __shared__ __align__(16) __hip_bfloat16 sB[BN * BKK];
    const int tid = threadIdx.x;
    const int w = tid >> 6, l = tid & 63;
    const int wr = w >> 1, wc = w & 1;
    const int row0 = blockIdx.y * BM;
    const int col0 = blockIdx.x * BN;
    const int srow = l >> 2;          // 0..15
    const int scol = (l & 3) * 8;     // 0,8,16,24

    f32x4 acc[4][4] = {};
    const int fr = l & 15;
    const int fc = (l >> 4) * 8;

    for (int k0 = 0; k0 < K; k0 += BKK) {
        for (int i = 0; i < 2; ++i) {
            int c = i * 4 + w;  // chunk 0..7, 16 rows each
            const __hip_bfloat16* ga = A + (size_t)(row0 + c * 16 + srow) * K + k0 + scol;
            __builtin_amdgcn_global_load_lds((const __attribute__((address_space(1))) void*)ga,
                                             (__attribute__((address_space(3))) void*)&sA[c * 16 * BKK], 16, 0, 0);
            const __hip_bfloat16* gb = Bt + (size_t)(col0 + c * 16 + srow) * K + k0 + scol;
            __builtin_amdgcn_global_load_lds((const __attribute__((address_space(1))) void*)gb,
                                             (__attribute__((address_space(3))) void*)&sB[c * 16 * BKK], 16, 0, 0);
        }
        __syncthreads();
        short8 af[4], bfr[4];
        for (int m = 0; m < 4; ++m)
            af[m] = *(const short8*)&sA[(wr * 64 + m * 16 + fr) * BKK + fc];
        for (int n = 0; n < 4; ++n)
            bfr[n] = *(const short8*)&sB[(wc * 64 + n * 16 + fr) * BKK + fc];
        for (int m = 0; m < 4; ++m)
            for (int n = 0; n < 4; ++n)
                acc[m][n] = __builtin_amdgcn_mfma_f32_16x16x32_bf16(af[m], bfr[n], acc[m][n], 0, 0, 0);
        __syncthreads();
    }
    const int fq = l >> 4;
    for (int m = 0; m < 4; ++m)
        for (int n = 0; n < 4; ++n)
            for (int r = 0; r < 4; ++r) {
                int row = row0 + wr * 64 + m * 16 + fq * 4 + r;
                int col = col0 + wc * 64 + n * 16 + fr;
                C[(size_t)row * N + col] = acc[m][n][r];
            }
}

// ---------------------------------------------------------------- fused RMSNorm + RoPE + pack
__global__ __launch_bounds__(256) void pack_kernel(
    const float* __restrict__ QKV, const float* __restrict__ cosp, const float* __restrict__ sinp,
    const float* __restrict__ qnw, const float* __restrict__ knw,
    __hip_bfloat16* __restrict__ Qh, __hip_bfloat16* __restrict__ Kh, __hip_bfloat16* __restrict__ Vt) {
    const int s = blockIdx.x;
    const int slot = blockIdx.y * 4 + (threadIdx.x >> 6);  // 0..39
    const int d = threadIdx.x & 63;
    const float* row = QKV + (size_t)s * 5120;
    float x1, x2;
    if (slot < 32)      { x1 = row[slot * 128 + d];              x2 = row[slot * 128 + d + 64]; }
    else if (slot < 36) { int t = slot - 32; x1 = row[4096 + t * 128 + d]; x2 = row[4096 + t * 128 + d + 64]; }
    else                { int t = slot - 36; x1 = row[4608 + t * 128 + d]; x2 = row[4608 + t * 128 + d + 64]; }

    if (slot >= 36) {   // V: just cast + transpose to (D,S)
        int t = slot - 36;
        Vt[((size_t)t * 128 + d) * SEQ + s]      = __float2bfloat16(x1);
        Vt[((size_t)t * 128 + d + 64) * SEQ + s] = __float2bfloat16(x2);
        return;
    }
    float ss = x1 * x1 + x2 * x2;
    for (int x = 1; x < 64; x <<= 1) ss += __shfl_xor(ss, x);
    float rs = rsqrtf(ss * (1.0f / 128.0f) + 1e-6f);
    float c = cosp[s * 128 + d], sn = sinp[s * 128 + d];  // cos[d]==cos[d+64]
    if (slot < 32) {
        float a = x1 * rs * qnw[d], b = x2 * rs * qnw[d + 64];
        float o1 = (a * c - b * sn) * QK_SCALE_LOG2;
        float o2 = (b * c + a * sn) * QK_SCALE_LOG2;
        Qh[((size_t)slot * SEQ + s) * 128 + d]      = __float2bfloat16(o1);
        Qh[((size_t)slot * SEQ + s) * 128 + d + 64] = __float2bfloat16(o2);
    } else {
        int t = slot - 32;
        float a = x1 * rs * knw[d], b = x2 * rs * knw[d + 64];
        float o1 = a * c - b * sn;
        float o2 = b * c + a * sn;
        Kh[((size_t)t * SEQ + s) * 128 + d]      = __float2bfloat16(o1);
        Kh[((size_t)t * SEQ + s) * 128 + d + 64] = __float2bfloat16(o2);
    }
}

// ---------------------------------------------------------------- causal GQA flash attention
// 1 wave per block, 16 q-rows per wave, KBLK=64, exp2-domain online softmax.
__global__ __launch_bounds__(64, 4) void attn_kernel(
    const __hip_bfloat16* __restrict__ Qh,  // [NH][S][D], scale*log2e folded
    const __hip_bfloat16* __restrict__ Kh,  // [NKV][S][D]
    const __hip_bfloat16* __restrict__ Vt,  // [NKV][D][S]
    __hip_bfloat16* __restrict__ Oa) {      // [S][NH*D]
    __shared__ __align__(16) __hip_bfloat16 sP[16 * 72];  // 16 q-rows x 64 k (pad to 72)
    const int l = threadIdx.x;
    const int h = blockIdx.y;
    const int hkv = h >> 3;
    const int qt = (int)gridDim.x - 1 - (int)blockIdx.x;   // longest work first
    const int qbase = qt * 16;
    const int fr = l & 15, g = l >> 4;
    const __hip_bfloat16* Qp = Qh + ((size_t)h * SEQ + qbase) * HDIM;
    const __hip_bfloat16* Kp = Kh + (size_t)hkv * SEQ * HDIM;
    const __hip_bfloat16* Vp = Vt + (size_t)hkv * HDIM * SEQ;

    short8 qf[4];
    for (int c = 0; c < 4; ++c)
        qf[c] = *(const short8*)&Qp[fr * HDIM + c * 32 + g * 8];

    f32x4 oacc[8] = {};
    float mrow[4], lrow[4];
    for (int r = 0; r < 4; ++r) { mrow[r] = -3.0e38f; lrow[r] = 0.f; }

    const int ntiles = ((qbase + 15) >> 6) + 1;
    for (int t = 0; t < ntiles; ++t) {
        const int kbase = t * 64;
        // ---- QK^T: 16 q x 64 k, 16 MFMAs in 4 independent chains
        f32x4 s[4] = {};
        for (int j = 0; j < 4; ++j) {
            const __hip_bfloat16* kp = Kp + (size_t)(kbase + j * 16 + fr) * HDIM + g * 8;
            for (int c = 0; c < 4; ++c) {
                short8 kf = *(const short8*)&kp[c * 32];
                s[j] = __builtin_amdgcn_mfma_f32_16x16x32_bf16(qf[c], kf, s[j], 0, 0, 0);
            }
        }
        // ---- online softmax (exp2 domain), causal mask
        float v[4][4], mloc[4];
        int grow = 0;
        for (int r = 0; r < 4; ++r) {
            const int qg = qbase + g * 4 + r;
            v[r][0] = (kbase + fr      <= qg) ? s[0][r] : -1e30f;
            v[r][1] = (kbase + 16 + fr <= qg) ? s[1][r] : -1e30f;
            v[r][2] = (kbase + 32 + fr <= qg) ? s[2][r] : -1e30f;
            v[r][3] = (kbase + 48 + fr <= qg) ? s[3][r] : -1e30f;
            float m = fmaxf(fmaxf(v[r][0], v[r][1]), fmaxf(v[r][2], v[r][3]));
            for (int x = 1; x < 16; x <<= 1) m = fmaxf(m, __shfl_xor(m, x));
            mloc[r] = m;
            grow |= (m > mrow[r]);
        }
        if (__any(grow)) {
            for (int r = 0; r < 4; ++r) {
                float mnew = fmaxf(mrow[r], mloc[r]);
                float corr = fast_exp2(mrow[r] - mnew);
                mrow[r] = mnew;
                lrow[r] *= corr;
                for (int dt = 0; dt < 8; ++dt) oacc[dt][r] *= corr;
            }
        }
        for (int r = 0; r < 4; ++r) {
            float e0 = fast_exp2(v[r][0] - mrow[r]);
            float e1 = fast_exp2(v[r][1] - mrow[r]);
            float e2 = fast_exp2(v[r][2] - mrow[r]);
            float e3 = fast_exp2(v[r][3] - mrow[r]);
            float sum = (e0 + e1) + (e2 + e3);
            for (int x = 1; x < 16; x <<= 1) sum += __shfl_xor(sum, x);
            lrow[r] += sum;
            const int prow = (g * 4 + r) * 72;
            sP[prow + fr]      = __float2bfloat16(e0);
            sP[prow + 16 + fr] = __float2bfloat16(e1);
            sP[prow + 32 + fr] = __float2bfloat16(e2);
            sP[prow + 48 + fr] = __float2bfloat16(e3);
        }
        // ---- PV: P(16x64) x V^T(64xD) -> 16 MFMAs
        short8 pa0 = *(const short8*)&sP[fr * 72 + g * 8];
        short8 pa1 = *(const short8*)&sP[fr * 72 + 32 + g * 8];
        const __hip_bfloat16* vp = Vp + (size_t)fr * SEQ + kbase + g * 8;
        for (int dt = 0; dt < 8; ++dt) {
            short8 vb0 = *(const short8*)&vp[(size_t)dt * 16 * SEQ];
            short8 vb1 = *(const short8*)&vp[(size_t)dt * 16 * SEQ + 32];
            oacc[dt] = __builtin_amdgcn_mfma_f32_16x16x32_bf16(pa0, vb0, oacc[dt], 0, 0, 0);
            oacc[dt] = __builtin_amdgcn_mfma_f32_16x16x32_bf16(pa1, vb1, oacc[dt], 0, 0, 0);
        }
    }
    float inv[4];
    for (int r = 0; r < 4; ++r) inv[r] = 1.0f / lrow[r];
    for (int dt = 0; dt < 8; ++dt)
        for (int r = 0; r < 4; ++r) {
            int qg = qbase + g * 4 + r;
            Oa[(size_t)qg * (NHEAD * HDIM) + h * HDIM + dt * 16 + fr] =
                __float2bfloat16(oacc[dt][r] * inv[r]);
        }
}

// ---------------------------------------------------------------- launch
extern "C" void kernel_launch(void* const* d_in, const int* in_sizes, int n_in,
                              void* d_out, int out_size, void* d_ws, size_t ws_size,
                              hipStream_t stream) {
    const float* hs   = (const float*)d_in[0];
    const float* cosp = (const float*)d_in[1];
    const float* sinp = (const float*)d_in[2];
    const float* wq   = (const float*)d_in[3];
    const float* wk   = (const float*)d_in[4];
    const float* wv   = (const float*)d_in[5];
    const float* wo   = (const float*)d_in[6];
    const float* qnw  = (const float*)d_in[7];
    const float* knw  = (const float*)d_in[8];
    float* out = (float*)d_out;
    char* ws = (char*)d_ws;

    // workspace layout (aliased stages)
    __hip_bfloat16* hsb    = (__hip_bfloat16*)(ws);                         // 8,388,608 B
    __hip_bfloat16* WqkvT  = (__hip_bfloat16*)(ws + 8388608);               // 20,971,520 B (5120x2048)
    __hip_bfloat16* WoT    = (__hip_bfloat16*)(ws + 29360128);              // 16,777,216 B (2048x4096)
    float*          QKV    = (float*)(ws + 46137344);                       // 41,943,040 B (2048x5120)
    // after QKV GEMM, WqkvT region is reused for packed Q/K/V:
    __hip_bfloat16* Qh     = (__hip_bfloat16*)(ws + 8388608);               // 16,777,216 B
    __hip_bfloat16* Kh     = (__hip_bfloat16*)(ws + 8388608 + 16777216);    //  2,097,152 B
    __hip_bfloat16* Vt     = (__hip_bfloat16*)(ws + 8388608 + 18874368);    //  2,097,152 B
    // after pack, QKV region is reused for attention output:
    __hip_bfloat16* Oa     = (__hip_bfloat16*)(ws + 46137344);              // 16,777,216 B

    cast_bf16_kernel<<<4096, 256, 0, stream>>>(hs, hsb, (SEQ * 2048) / 4);
    transpose_cast_kernel<<<dim3(128, 64), 256, 0, stream>>>(wq, WqkvT, 2048, 4096);
    transpose_cast_kernel<<<dim3(16, 64), 256, 0, stream>>>(wk, WqkvT + (size_t)4096 * 2048, 2048, 512);
    transpose_cast_kernel<<<dim3(16, 64), 256, 0, stream>>>(wv, WqkvT + (size_t)4608 * 2048, 2048, 512);
    transpose_cast_kernel<<<dim3(64, 128), 256, 0, stream>>>(wo, WoT, 4096, 2048);

    gemm_bt_kernel<<<dim3(40, 16), 256, 0, stream>>>(hsb, WqkvT, QKV, 2048, 5120, 2048);
    pack_kernel<<<dim3(2048, 10), 256, 0, stream>>>(QKV, cosp, sinp, qnw, knw, Qh, Kh, Vt);
    attn_kernel<<<dim3(128, 32), 64, 0, stream>>>(Qh, Kh, Vt, Oa);
    gemm_bt_kernel<<<dim3(16, 16), 256, 0, stream>>>(Oa, WoT, out, 2048, 2048, 4096);
}

// Round 4
// 296.897 us; speedup vs baseline: 2.2848x; 2.2101x over previous
//
#include <hip/hip_runtime.h>
#include <hip/hip_bf16.h>

using short8 = __attribute__((ext_vector_type(8))) short;
using f32x4  = __attribute__((ext_vector_type(4))) float;

#define SEQ 2048
#define NHEAD 32
#define NKVH 4
#define HDIM 128
// 1/sqrt(128) * log2(e)  -- exp2-domain softmax, folded into Q at pack time
#define QK_SCALE_LOG2 (0.08838834764831845f * 1.44269504088896340f)

__device__ __forceinline__ float fast_exp2(float x) { return __builtin_amdgcn_exp2f(x); }

// ---------------------------------------------------------------- cast fp32 -> bf16
__global__ void cast_bf16_kernel(const float* __restrict__ in, __hip_bfloat16* __restrict__ out, int n4) {
    int i = blockIdx.x * blockDim.x + threadIdx.x;
    if (i >= n4) return;
    float4 v = ((const float4*)in)[i];
    __hip_bfloat16 h[4] = {__float2bfloat16(v.x), __float2bfloat16(v.y),
                           __float2bfloat16(v.z), __float2bfloat16(v.w)};
    ((ushort4*)out)[i] = *(ushort4*)h;
}

// ---------------------------------------------------------------- transpose + cast: W (K,N) fp32 -> Wt (N,K) bf16
__global__ __launch_bounds__(256) void transpose_cast_kernel(
    const float* __restrict__ W, __hip_bfloat16* __restrict__ Wt, int K, int N) {
    __shared__ float tile[32][33];
    int tx = threadIdx.x & 31, ty = threadIdx.x >> 5;   // 32 x 8
    int nb = blockIdx.x * 32, kb = blockIdx.y * 32;
    for (int j = 0; j < 32; j += 8)
        tile[ty + j][tx] = W[(size_t)(kb + ty + j) * N + nb + tx];
    __syncthreads();
    for (int j = 0; j < 32; j += 8)
        Wt[(size_t)(nb + ty + j) * K + kb + tx] = __float2bfloat16(tile[tx][ty + j]);
}

// ---------------------------------------------------------------- GEMM: A(M,K)bf16 x Bt(N,K)bf16 -> C(M,N)fp32
#define BM 128
#define BN 128
#define BKK 32
__global__ __launch_bounds__(256) void gemm_bt_kernel(
    const __hip_bfloat16* __restrict__ A, const __hip_bfloat16* __restrict__ Bt,
    float* __restrict__ C, int M, int N, int K) {
    __shared__ __align__(16) __hip_bfloat16 sA[BM * BKK];
    __shared__ __align__(16) __hip_bfloat16 sB[BN * BKK];
    const int tid = threadIdx.x;
    const int w = tid >> 6, l = tid & 63;
    const int wr = w >> 1, wc = w & 1;
    const int row0 = blockIdx.y * BM;
    const int col0 = blockIdx.x * BN;
    const int srow = l >> 2;          // 0..15
    const int scol = (l & 3) * 8;     // 0,8,16,24

    f32x4 acc[4][4] = {};
    const int fr = l & 15;
    const int fc = (l >> 4) * 8;

    for (int k0 = 0; k0 < K; k0 += BKK) {
        for (int i = 0; i < 2; ++i) {
            int c = i * 4 + w;  // chunk 0..7, 16 rows each
            const __hip_bfloat16* ga = A + (size_t)(row0 + c * 16 + srow) * K + k0 + scol;
            __builtin_amdgcn_global_load_lds((const __attribute__((address_space(1))) void*)ga,
                                             (__attribute__((address_space(3))) void*)&sA[c * 16 * BKK], 16, 0, 0);
            const __hip_bfloat16* gb = Bt + (size_t)(col0 + c * 16 + srow) * K + k0 + scol;
            __builtin_amdgcn_global_load_lds((const __attribute__((address_space(1))) void*)gb,
                                             (__attribute__((address_space(3))) void*)&sB[c * 16 * BKK], 16, 0, 0);
        }
        __syncthreads();
        short8 af[4], bfr[4];
        for (int m = 0; m < 4; ++m)
            af[m] = *(const short8*)&sA[(wr * 64 + m * 16 + fr) * BKK + fc];
        for (int n = 0; n < 4; ++n)
            bfr[n] = *(const short8*)&sB[(wc * 64 + n * 16 + fr) * BKK + fc];
        for (int m = 0; m < 4; ++m)
            for (int n = 0; n < 4; ++n)
                acc[m][n] = __builtin_amdgcn_mfma_f32_16x16x32_bf16(af[m], bfr[n], acc[m][n], 0, 0, 0);
        __syncthreads();
    }
    const int fq = l >> 4;
    for (int m = 0; m < 4; ++m)
        for (int n = 0; n < 4; ++n)
            for (int r = 0; r < 4; ++r) {
                int row = row0 + wr * 64 + m * 16 + fq * 4 + r;
                int col = col0 + wc * 64 + n * 16 + fr;
                C[(size_t)row * N + col] = acc[m][n][r];
            }
}

// ---------------------------------------------------------------- fused RMSNorm + RoPE + pack
__global__ __launch_bounds__(256) void pack_kernel(
    const float* __restrict__ QKV, const float* __restrict__ cosp, const float* __restrict__ sinp,
    const float* __restrict__ qnw, const float* __restrict__ knw,
    __hip_bfloat16* __restrict__ Qh, __hip_bfloat16* __restrict__ Kh, __hip_bfloat16* __restrict__ Vt) {
    const int s = blockIdx.x;
    const int slot = blockIdx.y * 4 + (threadIdx.x >> 6);  // 0..39
    const int d = threadIdx.x & 63;
    const float* row = QKV + (size_t)s * 5120;
    float x1, x2;
    if (slot < 32)      { x1 = row[slot * 128 + d];              x2 = row[slot * 128 + d + 64]; }
    else if (slot < 36) { int t = slot - 32; x1 = row[4096 + t * 128 + d]; x2 = row[4096 + t * 128 + d + 64]; }
    else                { int t = slot - 36; x1 = row[4608 + t * 128 + d]; x2 = row[4608 + t * 128 + d + 64]; }

    if (slot >= 36) {   // V: just cast + transpose to (D,S)
        int t = slot - 36;
        Vt[((size_t)t * 128 + d) * SEQ + s]      = __float2bfloat16(x1);
        Vt[((size_t)t * 128 + d + 64) * SEQ + s] = __float2bfloat16(x2);
        return;
    }
    float ss = x1 * x1 + x2 * x2;
    for (int x = 1; x < 64; x <<= 1) ss += __shfl_xor(ss, x);
    float rs = rsqrtf(ss * (1.0f / 128.0f) + 1e-6f);
    float c = cosp[s * 128 + d], sn = sinp[s * 128 + d];  // cos[d]==cos[d+64]
    if (slot < 32) {
        float a = x1 * rs * qnw[d], b = x2 * rs * qnw[d + 64];
        float o1 = (a * c - b * sn) * QK_SCALE_LOG2;
        float o2 = (b * c + a * sn) * QK_SCALE_LOG2;
        Qh[((size_t)slot * SEQ + s) * 128 + d]      = __float2bfloat16(o1);
        Qh[((size_t)slot * SEQ + s) * 128 + d + 64] = __float2bfloat16(o2);
    } else {
        int t = slot - 32;
        float a = x1 * rs * knw[d], b = x2 * rs * knw[d + 64];
        float o1 = a * c - b * sn;
        float o2 = b * c + a * sn;
        Kh[((size_t)t * SEQ + s) * 128 + d]      = __float2bfloat16(o1);
        Kh[((size_t)t * SEQ + s) * 128 + d + 64] = __float2bfloat16(o2);
    }
}

// ---------------------------------------------------------------- causal GQA flash attention
// 4 waves/block = 4 q-heads of one kv-group, same 16-row q-range.
// K/V tiles (KVBLK=64) double-buffered in LDS via global_load_lds,
// XOR-swizzled (byte ^= (row&7)<<4) to kill the 32-way row-stride conflict.
__global__ __launch_bounds__(256, 2) void attn_kernel(
    const __hip_bfloat16* __restrict__ Qh,  // [NH][S][D], scale*log2e folded
    const __hip_bfloat16* __restrict__ Kh,  // [NKV][S][D]
    const __hip_bfloat16* __restrict__ Vt,  // [NKV][D][S]
    __hip_bfloat16* __restrict__ Oa) {      // [S][NH*D]
    __shared__ __align__(16) __hip_bfloat16 sK[2][64 * 128];   // 2 x 16 KB
    __shared__ __align__(16) __hip_bfloat16 sV[2][128 * 64];   // 2 x 16 KB
    __shared__ __align__(16) __hip_bfloat16 sP[4][16 * 72];    // per-wave P

    const int tid = threadIdx.x;
    const int w = tid >> 6, l = tid & 63;
    const int bx = blockIdx.x;
    const int y = bx & 7;                      // kv-slice -> XCD (wgid%8)
    const int qt = 127 - (bx >> 3);            // longest work first
    const int qbase = qt * 16;
    const int hkv = y >> 1;
    const int h = y * 4 + w;                   // this wave's q-head
    const int fr = l & 15, g = l >> 4;

    const __hip_bfloat16* Qp = Qh + ((size_t)h * SEQ + qbase) * HDIM;
    const __hip_bfloat16* Kp = Kh + (size_t)hkv * SEQ * HDIM;
    const __hip_bfloat16* Vp = Vt + (size_t)hkv * HDIM * SEQ;
    __hip_bfloat16* myP = &sP[w][0];

    short8 qf[4];
    for (int c = 0; c < 4; ++c)
        qf[c] = *(const short8*)&Qp[fr * HDIM + c * 32 + g * 8];

    f32x4 oacc[8] = {};
    float mrow[4], lrow[4];
    for (int r = 0; r < 4; ++r) { mrow[r] = -3.0e38f; lrow[r] = 0.f; }

    const int xr = (fr & 7) << 4;              // XOR-swizzle byte offset (read side)
    const int ntiles = ((qbase + 15) >> 6) + 1;

    // stage K(64x128) + V(128x64) tile into buf; linear LDS dest, pre-swizzled global src
    auto stage = [&](int buf, int kbase) {
        for (int i = 0; i < 4; ++i) {
            int blk = i * 4 + w;               // 0..15, uniform per wave
            {   // K: row = blk*4 + (l>>4), stored col = (l&15)*16 bytes
                int row = blk * 4 + (l >> 4);
                int cb = ((l & 15) * 16) ^ ((row & 7) << 4);
                const __hip_bfloat16* src = Kp + (size_t)(kbase + row) * HDIM + (cb >> 1);
                __builtin_amdgcn_global_load_lds((const __attribute__((address_space(1))) void*)src,
                    (__attribute__((address_space(3))) void*)&sK[buf][blk * 512], 16, 0, 0);
            }
            {   // V: row(d) = blk*8 + (l>>3), stored col = (l&7)*16 bytes
                int row = blk * 8 + (l >> 3);
                int cb = ((l & 7) * 16) ^ ((row & 7) << 4);
                const __hip_bfloat16* src = Vp + (size_t)row * SEQ + kbase + (cb >> 1);
                __builtin_amdgcn_global_load_lds((const __attribute__((address_space(1))) void*)src,
                    (__attribute__((address_space(3))) void*)&sV[buf][blk * 512], 16, 0, 0);
            }
        }
    };

    stage(0, 0);
    __syncthreads();                            // drains vmcnt(0): tile 0 ready

    for (int t = 0; t < ntiles; ++t) {
        const int kbase = t * 64;
        const int buf = t & 1;
        if (t + 1 < ntiles) stage(buf ^ 1, kbase + 64);   // overlap with compute

        // ---- QK^T: 16 q x 64 k from swizzled LDS
        f32x4 s[4] = {};
        for (int j = 0; j < 4; ++j) {
            const __hip_bfloat16* kp = &sK[buf][(j * 16 + fr) * 128];
            for (int c = 0; c < 4; ++c) {
                short8 kf = *(const short8*)&kp[((c * 64 + g * 16) ^ xr) >> 1];
                s[j] = __builtin_amdgcn_mfma_f32_16x16x32_bf16(qf[c], kf, s[j], 0, 0, 0);
            }
        }
        // ---- online softmax (exp2 domain), causal mask
        float v[4][4], mloc[4];
        int grow = 0;
        for (int r = 0; r < 4; ++r) {
            const int qg = qbase + g * 4 + r;
            v[r][0] = (kbase + fr      <= qg) ? s[0][r] : -1e30f;
            v[r][1] = (kbase + 16 + fr <= qg) ? s[1][r] : -1e30f;
            v[r][2] = (kbase + 32 + fr <= qg) ? s[2][r] : -1e30f;
            v[r][3] = (kbase + 48 + fr <= qg) ? s[3][r] : -1e30f;
            float m = fmaxf(fmaxf(v[r][0], v[r][1]), fmaxf(v[r][2], v[r][3]));
            for (int x = 1; x < 16; x <<= 1) m = fmaxf(m, __shfl_xor(m, x));
            mloc[r] = m;
            grow |= (m > mrow[r]);
        }
        if (__any(grow)) {
            for (int r = 0; r < 4; ++r) {
                float mnew = fmaxf(mrow[r], mloc[r]);
                float corr = fast_exp2(mrow[r] - mnew);
                mrow[r] = mnew;
                lrow[r] *= corr;
                for (int dt = 0; dt < 8; ++dt) oacc[dt][r] *= corr;
            }
        }
        for (int r = 0; r < 4; ++r) {
            float e0 = fast_exp2(v[r][0] - mrow[r]);
            float e1 = fast_exp2(v[r][1] - mrow[r]);
            float e2 = fast_exp2(v[r][2] - mrow[r]);
            float e3 = fast_exp2(v[r][3] - mrow[r]);
            float sum = (e0 + e1) + (e2 + e3);
            for (int x = 1; x < 16; x <<= 1) sum += __shfl_xor(sum, x);
            lrow[r] += sum;
            const int prow = (g * 4 + r) * 72;
            myP[prow + fr]      = __float2bfloat16(e0);
            myP[prow + 16 + fr] = __float2bfloat16(e1);
            myP[prow + 32 + fr] = __float2bfloat16(e2);
            myP[prow + 48 + fr] = __float2bfloat16(e3);
        }
        // ---- PV: P(16x64) x V^T(64xD) from swizzled LDS
        short8 pa0 = *(const short8*)&myP[fr * 72 + g * 8];
        short8 pa1 = *(const short8*)&myP[fr * 72 + 32 + g * 8];
        for (int dt = 0; dt < 8; ++dt) {
            const __hip_bfloat16* vp = &sV[buf][(dt * 16 + fr) * 64];
            short8 vb0 = *(const short8*)&vp[((g * 16)      ^ xr) >> 1];
            short8 vb1 = *(const short8*)&vp[((g * 16 + 64) ^ xr) >> 1];
            oacc[dt] = __builtin_amdgcn_mfma_f32_16x16x32_bf16(pa0, vb0, oacc[dt], 0, 0, 0);
            oacc[dt] = __builtin_amdgcn_mfma_f32_16x16x32_bf16(pa1, vb1, oacc[dt], 0, 0, 0);
        }
        __syncthreads();   // next tile staged (vmcnt 0) + all waves done with buf[t]
    }

    float inv[4];
    for (int r = 0; r < 4; ++r) inv[r] = 1.0f / lrow[r];
    for (int dt = 0; dt < 8; ++dt)
        for (int r = 0; r < 4; ++r) {
            int qg = qbase + g * 4 + r;
            Oa[(size_t)qg * (NHEAD * HDIM) + h * HDIM + dt * 16 + fr] =
                __float2bfloat16(oacc[dt][r] * inv[r]);
        }
}

// ---------------------------------------------------------------- launch
extern "C" void kernel_launch(void* const* d_in, const int* in_sizes, int n_in,
                              void* d_out, int out_size, void* d_ws, size_t ws_size,
                              hipStream_t stream) {
    const float* hs   = (const float*)d_in[0];
    const float* cosp = (const float*)d_in[1];
    const float* sinp = (const float*)d_in[2];
    const float* wq   = (const float*)d_in[3];
    const float* wk   = (const float*)d_in[4];
    const float* wv   = (const float*)d_in[5];
    const float* wo   = (const float*)d_in[6];
    const float* qnw  = (const float*)d_in[7];
    const float* knw  = (const float*)d_in[8];
    float* out = (float*)d_out;
    char* ws = (char*)d_ws;

    // workspace layout (aliased stages)
    __hip_bfloat16* hsb    = (__hip_bfloat16*)(ws);                         // 8,388,608 B
    __hip_bfloat16* WqkvT  = (__hip_bfloat16*)(ws + 8388608);               // 20,971,520 B (5120x2048)
    __hip_bfloat16* WoT    = (__hip_bfloat16*)(ws + 29360128);              // 16,777,216 B (2048x4096)
    float*          QKV    = (float*)(ws + 46137344);                       // 41,943,040 B (2048x5120)
    // after QKV GEMM, WqkvT region is reused for packed Q/K/V:
    __hip_bfloat16* Qh     = (__hip_bfloat16*)(ws + 8388608);               // 16,777,216 B
    __hip_bfloat16* Kh     = (__hip_bfloat16*)(ws + 8388608 + 16777216);    //  2,097,152 B
    __hip_bfloat16* Vt     = (__hip_bfloat16*)(ws + 8388608 + 18874368);    //  2,097,152 B
    // after pack, QKV region is reused for attention output:
    __hip_bfloat16* Oa     = (__hip_bfloat16*)(ws + 46137344);              // 16,777,216 B

    cast_bf16_kernel<<<4096, 256, 0, stream>>>(hs, hsb, (SEQ * 2048) / 4);
    transpose_cast_kernel<<<dim3(128, 64), 256, 0, stream>>>(wq, WqkvT, 2048, 4096);
    transpose_cast_kernel<<<dim3(16, 64), 256, 0, stream>>>(wk, WqkvT + (size_t)4096 * 2048, 2048, 512);
    transpose_cast_kernel<<<dim3(16, 64), 256, 0, stream>>>(wv, WqkvT + (size_t)4608 * 2048, 2048, 512);
    transpose_cast_kernel<<<dim3(64, 128), 256, 0, stream>>>(wo, WoT, 4096, 2048);

    gemm_bt_kernel<<<dim3(40, 16), 256, 0, stream>>>(hsb, WqkvT, QKV, 2048, 5120, 2048);
    pack_kernel<<<dim3(2048, 10), 256, 0, stream>>>(QKV, cosp, sinp, qnw, knw, Qh, Kh, Vt);
    attn_kernel<<<dim3(1024), 256, 0, stream>>>(Qh, Kh, Vt, Oa);
    gemm_bt_kernel<<<dim3(16, 16), 256, 0, stream>>>(Oa, WoT, out, 2048, 2048, 4096);
}

// Round 5
// 263.554 us; speedup vs baseline: 2.5738x; 1.1265x over previous
//
#include <hip/hip_runtime.h>
#include <hip/hip_bf16.h>

using short8 = __attribute__((ext_vector_type(8))) short;
using f32x4  = __attribute__((ext_vector_type(4))) float;

#define SEQ 2048
#define NHEAD 32
#define NKVH 4
#define HDIM 128
// 1/sqrt(128) * log2(e)  -- exp2-domain softmax, folded into Q at pack time
#define QK_SCALE_LOG2 (0.08838834764831845f * 1.44269504088896340f)

__device__ __forceinline__ float fast_exp2(float x) { return __builtin_amdgcn_exp2f(x); }

// ---------------------------------------------------------------- cast fp32 -> bf16
__global__ void cast_bf16_kernel(const float* __restrict__ in, __hip_bfloat16* __restrict__ out, int n4) {
    int i = blockIdx.x * blockDim.x + threadIdx.x;
    if (i >= n4) return;
    float4 v = ((const float4*)in)[i];
    __hip_bfloat16 h[4] = {__float2bfloat16(v.x), __float2bfloat16(v.y),
                           __float2bfloat16(v.z), __float2bfloat16(v.w)};
    ((ushort4*)out)[i] = *(ushort4*)h;
}

// ---------------------------------------------------------------- fp32 partial add: out = a + b
__global__ void add2_kernel(const float* __restrict__ a, const float* __restrict__ b,
                            float* __restrict__ o, int n4) {
    int i = blockIdx.x * blockDim.x + threadIdx.x;
    if (i >= n4) return;
    float4 x = ((const float4*)a)[i];
    float4 y = ((const float4*)b)[i];
    float4 z = {x.x + y.x, x.y + y.y, x.z + y.z, x.w + y.w};
    ((float4*)o)[i] = z;
}

// ---------------------------------------------------------------- transpose + cast: W (K,N) fp32 -> Wt (N,K) bf16
__global__ __launch_bounds__(256) void transpose_cast_kernel(
    const float* __restrict__ W, __hip_bfloat16* __restrict__ Wt, int K, int N) {
    __shared__ float tile[32][33];
    int tx = threadIdx.x & 31, ty = threadIdx.x >> 5;   // 32 x 8
    int nb = blockIdx.x * 32, kb = blockIdx.y * 32;
    for (int j = 0; j < 32; j += 8)
        tile[ty + j][tx] = W[(size_t)(kb + ty + j) * N + nb + tx];
    __syncthreads();
    for (int j = 0; j < 32; j += 8)
        Wt[(size_t)(nb + ty + j) * K + kb + tx] = __float2bfloat16(tile[tx][ty + j]);
}

// ---------------------------------------------------------------- GEMM: A(M,Kext)bf16 x Bt(N,Kext)bf16 -> C(M,N)fp32
// ld = leading dim of A and Bt. blockIdx.z selects a K-slice (split-K):
// A/Bt advance by koff elements, C advances by czstride elements.
#define BM 128
#define BN 128
#define BKK 32
__global__ __launch_bounds__(256) void gemm_bt_kernel(
    const __hip_bfloat16* __restrict__ A, const __hip_bfloat16* __restrict__ Bt,
    float* __restrict__ C, int M, int N, int Kext, int ld, int koff, long long czstride) {
    A  += (size_t)blockIdx.z * koff;
    Bt += (size_t)blockIdx.z * koff;
    C  += (size_t)blockIdx.z * czstride;
    __shared__ __align__(16) __hip_bfloat16 sA[BM * BKK];
    __shared__ __align__(16) __hip_bfloat16 sB[BN * BKK];
    const int tid = threadIdx.x;
    const int w = tid >> 6, l = tid & 63;
    const int wr = w >> 1, wc = w & 1;
    const int row0 = blockIdx.y * BM;
    const int col0 = blockIdx.x * BN;
    const int srow = l >> 2;          // 0..15
    const int scol = (l & 3) * 8;     // 0,8,16,24

    f32x4 acc[4][4] = {};
    const int fr = l & 15;
    const int fc = (l >> 4) * 8;

    for (int k0 = 0; k0 < Kext; k0 += BKK) {
        for (int i = 0; i < 2; ++i) {
            int c = i * 4 + w;  // chunk 0..7, 16 rows each
            const __hip_bfloat16* ga = A + (size_t)(row0 + c * 16 + srow) * ld + k0 + scol;
            __builtin_amdgcn_global_load_lds((const __attribute__((address_space(1))) void*)ga,
                                             (__attribute__((address_space(3))) void*)&sA[c * 16 * BKK], 16, 0, 0);
            const __hip_bfloat16* gb = Bt + (size_t)(col0 + c * 16 + srow) * ld + k0 + scol;
            __builtin_amdgcn_global_load_lds((const __attribute__((address_space(1))) void*)gb,
                                             (__attribute__((address_space(3))) void*)&sB[c * 16 * BKK], 16, 0, 0);
        }
        __syncthreads();
        short8 af[4], bfr[4];
        for (int m = 0; m < 4; ++m)
            af[m] = *(const short8*)&sA[(wr * 64 + m * 16 + fr) * BKK + fc];
        for (int n = 0; n < 4; ++n)
            bfr[n] = *(const short8*)&sB[(wc * 64 + n * 16 + fr) * BKK + fc];
        for (int m = 0; m < 4; ++m)
            for (int n = 0; n < 4; ++n)
                acc[m][n] = __builtin_amdgcn_mfma_f32_16x16x32_bf16(af[m], bfr[n], acc[m][n], 0, 0, 0);
        __syncthreads();
    }
    const int fq = l >> 4;
    for (int m = 0; m < 4; ++m)
        for (int n = 0; n < 4; ++n)
            for (int r = 0; r < 4; ++r) {
                int row = row0 + wr * 64 + m * 16 + fq * 4 + r;
                int col = col0 + wc * 64 + n * 16 + fr;
                C[(size_t)row * N + col] = acc[m][n][r];
            }
}

// ---------------------------------------------------------------- fused RMSNorm + RoPE + pack
__global__ __launch_bounds__(256) void pack_kernel(
    const float* __restrict__ QKV, const float* __restrict__ cosp, const float* __restrict__ sinp,
    const float* __restrict__ qnw, const float* __restrict__ knw,
    __hip_bfloat16* __restrict__ Qh, __hip_bfloat16* __restrict__ Kh, __hip_bfloat16* __restrict__ Vt) {
    const int s = blockIdx.x;
    const int slot = blockIdx.y * 4 + (threadIdx.x >> 6);  // 0..39
    const int d = threadIdx.x & 63;
    const float* row = QKV + (size_t)s * 5120;
    float x1, x2;
    if (slot < 32)      { x1 = row[slot * 128 + d];              x2 = row[slot * 128 + d + 64]; }
    else if (slot < 36) { int t = slot - 32; x1 = row[4096 + t * 128 + d]; x2 = row[4096 + t * 128 + d + 64]; }
    else                { int t = slot - 36; x1 = row[4608 + t * 128 + d]; x2 = row[4608 + t * 128 + d + 64]; }

    if (slot >= 36) {   // V: just cast + transpose to (D,S)
        int t = slot - 36;
        Vt[((size_t)t * 128 + d) * SEQ + s]      = __float2bfloat16(x1);
        Vt[((size_t)t * 128 + d + 64) * SEQ + s] = __float2bfloat16(x2);
        return;
    }
    float ss = x1 * x1 + x2 * x2;
    for (int x = 1; x < 64; x <<= 1) ss += __shfl_xor(ss, x);
    float rs = rsqrtf(ss * (1.0f / 128.0f) + 1e-6f);
    float c = cosp[s * 128 + d], sn = sinp[s * 128 + d];  // cos[d]==cos[d+64]
    if (slot < 32) {
        float a = x1 * rs * qnw[d], b = x2 * rs * qnw[d + 64];
        float o1 = (a * c - b * sn) * QK_SCALE_LOG2;
        float o2 = (b * c + a * sn) * QK_SCALE_LOG2;
        Qh[((size_t)slot * SEQ + s) * 128 + d]      = __float2bfloat16(o1);
        Qh[((size_t)slot * SEQ + s) * 128 + d + 64] = __float2bfloat16(o2);
    } else {
        int t = slot - 32;
        float a = x1 * rs * knw[d], b = x2 * rs * knw[d + 64];
        float o1 = a * c - b * sn;
        float o2 = b * c + a * sn;
        Kh[((size_t)t * SEQ + s) * 128 + d]      = __float2bfloat16(o1);
        Kh[((size_t)t * SEQ + s) * 128 + d + 64] = __float2bfloat16(o2);
    }
}

// ---------------------------------------------------------------- causal GQA flash attention
// 4 waves/block = 4 q-heads of one kv-group, same 16-row q-range.
// K/V tiles (KVBLK=64) double-buffered in LDS via global_load_lds,
// XOR-swizzled (byte ^= (row&7)<<4). Defer-max (THR=12 exp2) + deferred l-reduce.
__global__ __launch_bounds__(256, 2) void attn_kernel(
    const __hip_bfloat16* __restrict__ Qh,  // [NH][S][D], scale*log2e folded
    const __hip_bfloat16* __restrict__ Kh,  // [NKV][S][D]
    const __hip_bfloat16* __restrict__ Vt,  // [NKV][D][S]
    __hip_bfloat16* __restrict__ Oa) {      // [S][NH*D]
    __shared__ __align__(16) __hip_bfloat16 sK[2][64 * 128];   // 2 x 16 KB
    __shared__ __align__(16) __hip_bfloat16 sV[2][128 * 64];   // 2 x 16 KB
    __shared__ __align__(16) __hip_bfloat16 sP[4][16 * 72];    // per-wave P

    const int tid = threadIdx.x;
    const int w = tid >> 6, l = tid & 63;
    const int bx = blockIdx.x;
    const int y = bx & 7;                      // kv-slice -> XCD (wgid%8)
    const int qt = 127 - (bx >> 3);            // longest work first
    const int qbase = qt * 16;
    const int hkv = y >> 1;
    const int h = y * 4 + w;                   // this wave's q-head
    const int fr = l & 15, g = l >> 4;

    const __hip_bfloat16* Qp = Qh + ((size_t)h * SEQ + qbase) * HDIM;
    const __hip_bfloat16* Kp = Kh + (size_t)hkv * SEQ * HDIM;
    const __hip_bfloat16* Vp = Vt + (size_t)hkv * HDIM * SEQ;
    __hip_bfloat16* myP = &sP[w][0];

    short8 qf[4];
    for (int c = 0; c < 4; ++c)
        qf[c] = *(const short8*)&Qp[fr * HDIM + c * 32 + g * 8];

    f32x4 oacc[8] = {};
    float mrow[4], lpart[4];
    for (int r = 0; r < 4; ++r) { mrow[r] = -3.0e38f; lpart[r] = 0.f; }

    const int xr = (fr & 7) << 4;              // XOR-swizzle byte offset (read side)
    const int ntiles = ((qbase + 15) >> 6) + 1;

    // stage K(64x128) + V(128x64) tile into buf; linear LDS dest, pre-swizzled global src
    auto stage = [&](int buf, int kbase) {
        for (int i = 0; i < 4; ++i) {
            int blk = i * 4 + w;               // 0..15, uniform per wave
            {   // K: row = blk*4 + (l>>4), stored col = (l&15)*16 bytes
                int row = blk * 4 + (l >> 4);
                int cb = ((l & 15) * 16) ^ ((row & 7) << 4);
                const __hip_bfloat16* src = Kp + (size_t)(kbase + row) * HDIM + (cb >> 1);
                __builtin_amdgcn_global_load_lds((const __attribute__((address_space(1))) void*)src,
                    (__attribute__((address_space(3))) void*)&sK[buf][blk * 512], 16, 0, 0);
            }
            {   // V: row(d) = blk*8 + (l>>3), stored col = (l&7)*16 bytes
                int row = blk * 8 + (l >> 3);
                int cb = ((l & 7) * 16) ^ ((row & 7) << 4);
                const __hip_bfloat16* src = Vp + (size_t)row * SEQ + kbase + (cb >> 1);
                __builtin_amdgcn_global_load_lds((const __attribute__((address_space(1))) void*)src,
                    (__attribute__((address_space(3))) void*)&sV[buf][blk * 512], 16, 0, 0);
            }
        }
    };

    stage(0, 0);
    __syncthreads();                            // drains vmcnt(0): tile 0 ready

    for (int t = 0; t < ntiles; ++t) {
        const int kbase = t * 64;
        const int buf = t & 1;
        if (t + 1 < ntiles) stage(buf ^ 1, kbase + 64);   // overlap with compute

        // ---- QK^T: 16 q x 64 k from swizzled LDS
        f32x4 s[4] = {};
        for (int j = 0; j < 4; ++j) {
            const __hip_bfloat16* kp = &sK[buf][(j * 16 + fr) * 128];
            for (int c = 0; c < 4; ++c) {
                short8 kf = *(const short8*)&kp[((c * 64 + g * 16) ^ xr) >> 1];
                s[j] = __builtin_amdgcn_mfma_f32_16x16x32_bf16(qf[c], kf, s[j], 0, 0, 0);
            }
        }
        // ---- online softmax (exp2 domain), causal mask, defer-max THR=12
        float v[4][4], mloc[4];
        const bool full = (kbase + 63 <= qbase);   // wave-uniform: no masking needed
        for (int r = 0; r < 4; ++r) {
            if (full) {
                v[r][0] = s[0][r]; v[r][1] = s[1][r]; v[r][2] = s[2][r]; v[r][3] = s[3][r];
            } else {
                const int qg = qbase + g * 4 + r;
                v[r][0] = (kbase + fr      <= qg) ? s[0][r] : -1e30f;
                v[r][1] = (kbase + 16 + fr <= qg) ? s[1][r] : -1e30f;
                v[r][2] = (kbase + 32 + fr <= qg) ? s[2][r] : -1e30f;
                v[r][3] = (kbase + 48 + fr <= qg) ? s[3][r] : -1e30f;
            }
            float m = fmaxf(fmaxf(v[r][0], v[r][1]), fmaxf(v[r][2], v[r][3]));
            for (int x = 1; x < 16; x <<= 1) m = fmaxf(m, __shfl_xor(m, x));
            mloc[r] = m;
        }
        int grow = (mloc[0] > mrow[0] + 12.0f) | (mloc[1] > mrow[1] + 12.0f) |
                   (mloc[2] > mrow[2] + 12.0f) | (mloc[3] > mrow[3] + 12.0f);
        if (__any(grow)) {
            for (int r = 0; r < 4; ++r) {
                float mnew = fmaxf(mrow[r], mloc[r]);
                float corr = fast_exp2(mrow[r] - mnew);
                mrow[r] = mnew;
                lpart[r] *= corr;
                for (int dt = 0; dt < 8; ++dt) oacc[dt][r] *= corr;
            }
        }
        for (int r = 0; r < 4; ++r) {
            float e0 = fast_exp2(v[r][0] - mrow[r]);
            float e1 = fast_exp2(v[r][1] - mrow[r]);
            float e2 = fast_exp2(v[r][2] - mrow[r]);
            float e3 = fast_exp2(v[r][3] - mrow[r]);
            lpart[r] += (e0 + e1) + (e2 + e3);
            const int prow = (g * 4 + r) * 72;
            myP[prow + fr]      = __float2bfloat16(e0);
            myP[prow + 16 + fr] = __float2bfloat16(e1);
            myP[prow + 32 + fr] = __float2bfloat16(e2);
            myP[prow + 48 + fr] = __float2bfloat16(e3);
        }
        // ---- PV: P(16x64) x V^T(64xD) from swizzled LDS
        short8 pa0 = *(const short8*)&myP[fr * 72 + g * 8];
        short8 pa1 = *(const short8*)&myP[fr * 72 + 32 + g * 8];
        for (int dt = 0; dt < 8; ++dt) {
            const __hip_bfloat16* vp = &sV[buf][(dt * 16 + fr) * 64];
            short8 vb0 = *(const short8*)&vp[((g * 16)      ^ xr) >> 1];
            short8 vb1 = *(const short8*)&vp[((g * 16 + 64) ^ xr) >> 1];
            oacc[dt] = __builtin_amdgcn_mfma_f32_16x16x32_bf16(pa0, vb0, oacc[dt], 0, 0, 0);
            oacc[dt] = __builtin_amdgcn_mfma_f32_16x16x32_bf16(pa1, vb1, oacc[dt], 0, 0, 0);
        }
        __syncthreads();   // next tile staged (vmcnt 0) + all waves done with buf[t]
    }

    float inv[4];
    for (int r = 0; r < 4; ++r) {
        float lsum = lpart[r];
        for (int x = 1; x < 16; x <<= 1) lsum += __shfl_xor(lsum, x);
        inv[r] = 1.0f / lsum;
    }
    for (int dt = 0; dt < 8; ++dt)
        for (int r = 0; r < 4; ++r) {
            int qg = qbase + g * 4 + r;
            Oa[(size_t)qg * (NHEAD * HDIM) + h * HDIM + dt * 16 + fr] =
                __float2bfloat16(oacc[dt][r] * inv[r]);
        }
}

// ---------------------------------------------------------------- launch
extern "C" void kernel_launch(void* const* d_in, const int* in_sizes, int n_in,
                              void* d_out, int out_size, void* d_ws, size_t ws_size,
                              hipStream_t stream) {
    const float* hs   = (const float*)d_in[0];
    const float* cosp = (const float*)d_in[1];
    const float* sinp = (const float*)d_in[2];
    const float* wq   = (const float*)d_in[3];
    const float* wk   = (const float*)d_in[4];
    const float* wv   = (const float*)d_in[5];
    const float* wo   = (const float*)d_in[6];
    const float* qnw  = (const float*)d_in[7];
    const float* knw  = (const float*)d_in[8];
    float* out = (float*)d_out;
    char* ws = (char*)d_ws;

    // workspace layout (aliased stages, ws_size >= 88,080,384 B)
    __hip_bfloat16* hsb    = (__hip_bfloat16*)(ws);                         // 8,388,608 B
    __hip_bfloat16* WqkvT  = (__hip_bfloat16*)(ws + 8388608);               // 20,971,520 B (5120x2048)
    __hip_bfloat16* WoT    = (__hip_bfloat16*)(ws + 29360128);              // 16,777,216 B (2048x4096)
    float*          QKV    = (float*)(ws + 46137344);                       // 41,943,040 B (2048x5120)
    // after QKV GEMM, WqkvT region is reused for packed Q/K/V:
    __hip_bfloat16* Qh     = (__hip_bfloat16*)(ws + 8388608);               // 16,777,216 B
    __hip_bfloat16* Kh     = (__hip_bfloat16*)(ws + 8388608 + 16777216);    //  2,097,152 B
    __hip_bfloat16* Vt     = (__hip_bfloat16*)(ws + 8388608 + 18874368);    //  2,097,152 B
    // after pack, QKV region is reused for attention output:
    __hip_bfloat16* Oa     = (__hip_bfloat16*)(ws + 46137344);              // 16,777,216 B
    // after attn, Qh region and the QKV tail are reused for split-K partials:
    float*          P0     = (float*)(ws + 8388608);                        // 16,777,216 B
    float*          P1     = (float*)(ws + 62914560);                       // 16,777,216 B
    const long long czstride = (62914560LL - 8388608LL) / 4;                // elements

    cast_bf16_kernel<<<4096, 256, 0, stream>>>(hs, hsb, (SEQ * 2048) / 4);
    transpose_cast_kernel<<<dim3(128, 64), 256, 0, stream>>>(wq, WqkvT, 2048, 4096);
    transpose_cast_kernel<<<dim3(16, 64), 256, 0, stream>>>(wk, WqkvT + (size_t)4096 * 2048, 2048, 512);
    transpose_cast_kernel<<<dim3(16, 64), 256, 0, stream>>>(wv, WqkvT + (size_t)4608 * 2048, 2048, 512);
    transpose_cast_kernel<<<dim3(64, 128), 256, 0, stream>>>(wo, WoT, 4096, 2048);

    gemm_bt_kernel<<<dim3(40, 16, 1), 256, 0, stream>>>(hsb, WqkvT, QKV, 2048, 5120, 2048, 2048, 0, 0);
    pack_kernel<<<dim3(2048, 10), 256, 0, stream>>>(QKV, cosp, sinp, qnw, knw, Qh, Kh, Vt);
    attn_kernel<<<dim3(1024), 256, 0, stream>>>(Qh, Kh, Vt, Oa);
    // O-projection: split-K=2 (z-dim), 512 WGs concurrent, then reduce partials
    gemm_bt_kernel<<<dim3(16, 16, 2), 256, 0, stream>>>(Oa, WoT, P0, 2048, 2048, 2048, 4096, 2048, czstride);
    add2_kernel<<<4096, 256, 0, stream>>>(P0, P1, out, (2048 * 2048) / 4);
}

// Round 6
// 261.634 us; speedup vs baseline: 2.5927x; 1.0073x over previous
//
#include <hip/hip_runtime.h>
#include <hip/hip_bf16.h>

using short8 = __attribute__((ext_vector_type(8))) short;
using f32x4  = __attribute__((ext_vector_type(4))) float;

#define SEQ 2048
#define NHEAD 32
#define NKVH 4
#define HDIM 128
// 1/sqrt(128) * log2(e)  -- exp2-domain softmax, folded into Q at pack time
#define QK_SCALE_LOG2 (0.08838834764831845f * 1.44269504088896340f)

__device__ __forceinline__ float fast_exp2(float x) { return __builtin_amdgcn_exp2f(x); }

// ---------------------------------------------------------------- fused prep: cast hs + transpose wq/wk/wv
// blocks [0,4096): cast hs (2048x2048 fp32 -> bf16)
// blocks [4096,12288): wq (2048,4096) -> WqkvT rows 0..4095
// blocks [12288,13312): wk (2048,512) -> WqkvT rows 4096..4607
// blocks [13312,14336): wv (2048,512) -> WqkvT rows 4608..5119
__global__ __launch_bounds__(256) void prep_kernel(
    const float* __restrict__ hs, __hip_bfloat16* __restrict__ hsb,
    const float* __restrict__ wq, const float* __restrict__ wk, const float* __restrict__ wv,
    __hip_bfloat16* __restrict__ WqkvT) {
    const int b = blockIdx.x, tid = threadIdx.x;
    if (b < 4096) {
        int i = b * 256 + tid;
        float4 v = ((const float4*)hs)[i];
        __hip_bfloat16 h4[4] = {__float2bfloat16(v.x), __float2bfloat16(v.y),
                                __float2bfloat16(v.z), __float2bfloat16(v.w)};
        ((ushort4*)hsb)[i] = *(ushort4*)h4;
        return;
    }
    __shared__ float tile[32][33];
    const float* W; __hip_bfloat16* Wt; int N, nb, kb;
    if (b < 12288)      { int bb = b - 4096;  W = wq; Wt = WqkvT;                        N = 4096; nb = (bb & 127) * 32; kb = (bb >> 7) * 32; }
    else if (b < 13312) { int bb = b - 12288; W = wk; Wt = WqkvT + (size_t)4096 * 2048; N = 512;  nb = (bb & 15) * 32;  kb = (bb >> 4) * 32; }
    else                { int bb = b - 13312; W = wv; Wt = WqkvT + (size_t)4608 * 2048; N = 512;  nb = (bb & 15) * 32;  kb = (bb >> 4) * 32; }
    int tx = tid & 31, ty = tid >> 5;   // 32 x 8
    for (int j = 0; j < 32; j += 8)
        tile[ty + j][tx] = W[(size_t)(kb + ty + j) * N + nb + tx];
    __syncthreads();
    for (int j = 0; j < 32; j += 8)
        Wt[(size_t)(nb + ty + j) * 2048 + kb + tx] = __float2bfloat16(tile[tx][ty + j]);
}

// ---------------------------------------------------------------- transpose + cast: W (K,N) fp32 -> Wt (N,K) bf16
__global__ __launch_bounds__(256) void transpose_cast_kernel(
    const float* __restrict__ W, __hip_bfloat16* __restrict__ Wt, int K, int N) {
    __shared__ float tile[32][33];
    int tx = threadIdx.x & 31, ty = threadIdx.x >> 5;   // 32 x 8
    int nb = blockIdx.x * 32, kb = blockIdx.y * 32;
    for (int j = 0; j < 32; j += 8)
        tile[ty + j][tx] = W[(size_t)(kb + ty + j) * N + nb + tx];
    __syncthreads();
    for (int j = 0; j < 32; j += 8)
        Wt[(size_t)(nb + ty + j) * K + kb + tx] = __float2bfloat16(tile[tx][ty + j]);
}

// ---------------------------------------------------------------- fp32 partial add: out = a + b
__global__ void add2_kernel(const float* __restrict__ a, const float* __restrict__ b,
                            float* __restrict__ o, int n4) {
    int i = blockIdx.x * blockDim.x + threadIdx.x;
    if (i >= n4) return;
    float4 x = ((const float4*)a)[i];
    float4 y = ((const float4*)b)[i];
    float4 z = {x.x + y.x, x.y + y.y, x.z + y.z, x.w + y.w};
    ((float4*)o)[i] = z;
}

// ---------------------------------------------------------------- GEMM: A(M,*)bf16 x Bt(N,*)bf16 -> C(M,N)
// ld = leading dim of A and Bt. blockIdx.z = K-slice (split-K): A/Bt advance
// koff elements, C advances czstride elements. OutT in {float, __hip_bfloat16}.
#define BM 128
#define BN 128
#define BKK 32
template <typename OutT>
__global__ __launch_bounds__(256) void gemm_bt_kernel(
    const __hip_bfloat16* __restrict__ A, const __hip_bfloat16* __restrict__ Bt,
    OutT* __restrict__ C, int M, int N, int Kext, int ld, int koff, long long czstride) {
    A  += (size_t)blockIdx.z * koff;
    Bt += (size_t)blockIdx.z * koff;
    C  += (size_t)blockIdx.z * czstride;
    __shared__ __align__(16) __hip_bfloat16 sA[BM * BKK];
    __shared__ __align__(16) __hip_bfloat16 sB[BN * BKK];
    const int tid = threadIdx.x;
    const int w = tid >> 6, l = tid & 63;
    const int wr = w >> 1, wc = w & 1;
    const int row0 = blockIdx.y * BM;
    const int col0 = blockIdx.x * BN;
    const int srow = l >> 2;          // 0..15
    const int scol = (l & 3) * 8;     // 0,8,16,24

    f32x4 acc[4][4] = {};
    const int fr = l & 15;
    const int fc = (l >> 4) * 8;

    for (int k0 = 0; k0 < Kext; k0 += BKK) {
        for (int i = 0; i < 2; ++i) {
            int c = i * 4 + w;  // chunk 0..7, 16 rows each
            const __hip_bfloat16* ga = A + (size_t)(row0 + c * 16 + srow) * ld + k0 + scol;
            __builtin_amdgcn_global_load_lds((const __attribute__((address_space(1))) void*)ga,
                                             (__attribute__((address_space(3))) void*)&sA[c * 16 * BKK], 16, 0, 0);
            const __hip_bfloat16* gb = Bt + (size_t)(col0 + c * 16 + srow) * ld + k0 + scol;
            __builtin_amdgcn_global_load_lds((const __attribute__((address_space(1))) void*)gb,
                                             (__attribute__((address_space(3))) void*)&sB[c * 16 * BKK], 16, 0, 0);
        }
        __syncthreads();
        short8 af[4], bfr[4];
        for (int m = 0; m < 4; ++m)
            af[m] = *(const short8*)&sA[(wr * 64 + m * 16 + fr) * BKK + fc];
        for (int n = 0; n < 4; ++n)
            bfr[n] = *(const short8*)&sB[(wc * 64 + n * 16 + fr) * BKK + fc];
        for (int m = 0; m < 4; ++m)
            for (int n = 0; n < 4; ++n)
                acc[m][n] = __builtin_amdgcn_mfma_f32_16x16x32_bf16(af[m], bfr[n], acc[m][n], 0, 0, 0);
        __syncthreads();
    }
    const int fq = l >> 4;
    for (int m = 0; m < 4; ++m)
        for (int n = 0; n < 4; ++n)
            for (int r = 0; r < 4; ++r) {
                int row = row0 + wr * 64 + m * 16 + fq * 4 + r;
                int col = col0 + wc * 64 + n * 16 + fr;
                float v = acc[m][n][r];
                if constexpr (__is_same(OutT, float)) C[(size_t)row * N + col] = v;
                else C[(size_t)row * N + col] = __float2bfloat16(v);
            }
}

// ---------------------------------------------------------------- fused partial-add + RMSNorm + RoPE + pack
__global__ __launch_bounds__(256) void pack_kernel(
    const __hip_bfloat16* __restrict__ P0, const __hip_bfloat16* __restrict__ P1,
    const float* __restrict__ cosp, const float* __restrict__ sinp,
    const float* __restrict__ qnw, const float* __restrict__ knw,
    __hip_bfloat16* __restrict__ Qh, __hip_bfloat16* __restrict__ Kh, __hip_bfloat16* __restrict__ Vt) {
    const int s = blockIdx.x;
    const int slot = blockIdx.y * 4 + (threadIdx.x >> 6);  // 0..39
    const int d = threadIdx.x & 63;
    const __hip_bfloat16* r0 = P0 + (size_t)s * 5120;
    const __hip_bfloat16* r1 = P1 + (size_t)s * 5120;
    int o1i, o2i;
    if (slot < 32)      { o1i = slot * 128 + d;               o2i = o1i + 64; }
    else if (slot < 36) { o1i = 4096 + (slot - 32) * 128 + d; o2i = o1i + 64; }
    else                { o1i = 4608 + (slot - 36) * 128 + d; o2i = o1i + 64; }
    float x1 = __bfloat162float(r0[o1i]) + __bfloat162float(r1[o1i]);
    float x2 = __bfloat162float(r0[o2i]) + __bfloat162float(r1[o2i]);

    if (slot >= 36) {   // V: just cast + transpose to (D,S)
        int t = slot - 36;
        Vt[((size_t)t * 128 + d) * SEQ + s]      = __float2bfloat16(x1);
        Vt[((size_t)t * 128 + d + 64) * SEQ + s] = __float2bfloat16(x2);
        return;
    }
    float ss = x1 * x1 + x2 * x2;
    for (int x = 1; x < 64; x <<= 1) ss += __shfl_xor(ss, x);
    float rs = rsqrtf(ss * (1.0f / 128.0f) + 1e-6f);
    float c = cosp[s * 128 + d], sn = sinp[s * 128 + d];  // cos[d]==cos[d+64]
    if (slot < 32) {
        float a = x1 * rs * qnw[d], b = x2 * rs * qnw[d + 64];
        float o1 = (a * c - b * sn) * QK_SCALE_LOG2;
        float o2 = (b * c + a * sn) * QK_SCALE_LOG2;
        Qh[((size_t)slot * SEQ + s) * 128 + d]      = __float2bfloat16(o1);
        Qh[((size_t)slot * SEQ + s) * 128 + d + 64] = __float2bfloat16(o2);
    } else {
        int t = slot - 32;
        float a = x1 * rs * knw[d], b = x2 * rs * knw[d + 64];
        float o1 = a * c - b * sn;
        float o2 = b * c + a * sn;
        Kh[((size_t)t * SEQ + s) * 128 + d]      = __float2bfloat16(o1);
        Kh[((size_t)t * SEQ + s) * 128 + d + 64] = __float2bfloat16(o2);
    }
}

// ---------------------------------------------------------------- causal GQA flash attention
// 8 waves/block = ALL 8 q-heads of one kv-group, same 16-row q-range:
// K/V staged once per block (half the traffic of 4-wave version).
// K/V double-buffered via global_load_lds, XOR-swizzle byte^=(row&7)<<4.
// sP also XOR-swizzled (16x64 per wave). LDS = 32+32+16 = 80 KB -> 2 blocks/CU.
__global__ __launch_bounds__(512, 2) void attn_kernel(
    const __hip_bfloat16* __restrict__ Qh,  // [NH][S][D], scale*log2e folded
    const __hip_bfloat16* __restrict__ Kh,  // [NKV][S][D]
    const __hip_bfloat16* __restrict__ Vt,  // [NKV][D][S]
    __hip_bfloat16* __restrict__ Oa) {      // [S][NH*D]
    __shared__ __align__(16) __hip_bfloat16 sK[2][64 * 128];   // 2 x 16 KB
    __shared__ __align__(16) __hip_bfloat16 sV[2][128 * 64];   // 2 x 16 KB
    __shared__ __align__(16) __hip_bfloat16 sP[8][16 * 64];    // per-wave P, swizzled

    const int tid = threadIdx.x;
    const int w = tid >> 6, l = tid & 63;
    const int bx = blockIdx.x;
    const int hkv = bx & 3;
    const int qt = 127 - (bx >> 2);            // longest work first
    const int qbase = qt * 16;
    const int h = hkv * 8 + w;                 // this wave's q-head
    const int fr = l & 15, g = l >> 4;

    const __hip_bfloat16* Qp = Qh + ((size_t)h * SEQ + qbase) * HDIM;
    const __hip_bfloat16* Kp = Kh + (size_t)hkv * SEQ * HDIM;
    const __hip_bfloat16* Vp = Vt + (size_t)hkv * HDIM * SEQ;
    __hip_bfloat16* myP = &sP[w][0];

    short8 qf[4];
    for (int c = 0; c < 4; ++c)
        qf[c] = *(const short8*)&Qp[fr * HDIM + c * 32 + g * 8];

    f32x4 oacc[8] = {};
    float mrow[4], lpart[4];
    for (int r = 0; r < 4; ++r) { mrow[r] = -3.0e38f; lpart[r] = 0.f; }

    const int xr = (fr & 7) << 4;              // XOR-swizzle byte offset (read side)
    const int ntiles = ((qbase + 15) >> 6) + 1;

    // stage K(64x128) + V(128x64) tile; linear LDS dest, pre-swizzled global src.
    // 1024 16B-chunks each, 512 threads -> 2 per thread.
    auto stage = [&](int buf, int kbase) {
        for (int t2 = 0; t2 < 2; ++t2) {
            int chunk = t2 * 512 + tid;        // 0..1023
            {   // K: 16 chunks per row (256 B/row)
                int row = chunk >> 4;
                int cb = ((chunk & 15) * 16) ^ ((row & 7) << 4);
                const __hip_bfloat16* src = Kp + (size_t)(kbase + row) * HDIM + (cb >> 1);
                __builtin_amdgcn_global_load_lds((const __attribute__((address_space(1))) void*)src,
                    (__attribute__((address_space(3))) void*)&sK[buf][chunk * 8], 16, 0, 0);
            }
            {   // V: 8 chunks per row (128 B/row)
                int row = chunk >> 3;
                int cb = ((chunk & 7) * 16) ^ ((row & 7) << 4);
                const __hip_bfloat16* src = Vp + (size_t)row * SEQ + kbase + (cb >> 1);
                __builtin_amdgcn_global_load_lds((const __attribute__((address_space(1))) void*)src,
                    (__attribute__((address_space(3))) void*)&sV[buf][chunk * 8], 16, 0, 0);
            }
        }
    };

    stage(0, 0);
    __syncthreads();                            // drains vmcnt(0): tile 0 ready

    for (int t = 0; t < ntiles; ++t) {
        const int kbase = t * 64;
        const int buf = t & 1;
        if (t + 1 < ntiles) stage(buf ^ 1, kbase + 64);   // overlap with compute

        // ---- QK^T: 16 q x 64 k from swizzled LDS
        f32x4 s[4] = {};
        for (int j = 0; j < 4; ++j) {
            const __hip_bfloat16* kp = &sK[buf][(j * 16 + fr) * 128];
            for (int c = 0; c < 4; ++c) {
                short8 kf = *(const short8*)&kp[((c * 64 + g * 16) ^ xr) >> 1];
                s[j] = __builtin_amdgcn_mfma_f32_16x16x32_bf16(qf[c], kf, s[j], 0, 0, 0);
            }
        }
        // ---- online softmax (exp2 domain), causal mask, defer-max THR=12
        float v[4][4], mloc[4];
        const bool full = (kbase + 63 <= qbase);   // wave-uniform: no masking needed
        for (int r = 0; r < 4; ++r) {
            if (full) {
                v[r][0] = s[0][r]; v[r][1] = s[1][r]; v[r][2] = s[2][r]; v[r][3] = s[3][r];
            } else {
                const int qg = qbase + g * 4 + r;
                v[r][0] = (kbase + fr      <= qg) ? s[0][r] : -1e30f;
                v[r][1] = (kbase + 16 + fr <= qg) ? s[1][r] : -1e30f;
                v[r][2] = (kbase + 32 + fr <= qg) ? s[2][r] : -1e30f;
                v[r][3] = (kbase + 48 + fr <= qg) ? s[3][r] : -1e30f;
            }
            float m = fmaxf(fmaxf(v[r][0], v[r][1]), fmaxf(v[r][2], v[r][3]));
            for (int x = 1; x < 16; x <<= 1) m = fmaxf(m, __shfl_xor(m, x));
            mloc[r] = m;
        }
        int grow = (mloc[0] > mrow[0] + 12.0f) | (mloc[1] > mrow[1] + 12.0f) |
                   (mloc[2] > mrow[2] + 12.0f) | (mloc[3] > mrow[3] + 12.0f);
        if (__any(grow)) {
            for (int r = 0; r < 4; ++r) {
                float mnew = fmaxf(mrow[r], mloc[r]);
                float corr = fast_exp2(mrow[r] - mnew);
                mrow[r] = mnew;
                lpart[r] *= corr;
                for (int dt = 0; dt < 8; ++dt) oacc[dt][r] *= corr;
            }
        }
        for (int r = 0; r < 4; ++r) {
            float e0 = fast_exp2(v[r][0] - mrow[r]);
            float e1 = fast_exp2(v[r][1] - mrow[r]);
            float e2 = fast_exp2(v[r][2] - mrow[r]);
            float e3 = fast_exp2(v[r][3] - mrow[r]);
            lpart[r] += (e0 + e1) + (e2 + e3);
            const int row = g * 4 + r;
            const int xo = (row & 7) << 4;
            char* pb = (char*)myP;
            *(__hip_bfloat16*)(pb + ((row * 128 + fr * 2)      ^ xo)) = __float2bfloat16(e0);
            *(__hip_bfloat16*)(pb + ((row * 128 + 32 + fr * 2) ^ xo)) = __float2bfloat16(e1);
            *(__hip_bfloat16*)(pb + ((row * 128 + 64 + fr * 2) ^ xo)) = __float2bfloat16(e2);
            *(__hip_bfloat16*)(pb + ((row * 128 + 96 + fr * 2) ^ xo)) = __float2bfloat16(e3);
        }
        // ---- PV: P(16x64) x V^T(64xD) from swizzled LDS
        const int xp = (fr & 7) << 4;
        short8 pa0 = *(const short8*)((const char*)myP + ((fr * 128 + g * 16)      ^ xp));
        short8 pa1 = *(const short8*)((const char*)myP + ((fr * 128 + 64 + g * 16) ^ xp));
        for (int dt = 0; dt < 8; ++dt) {
            const __hip_bfloat16* vp = &sV[buf][(dt * 16 + fr) * 64];
            short8 vb0 = *(const short8*)&vp[((g * 16)      ^ xr) >> 1];
            short8 vb1 = *(const short8*)&vp[((g * 16 + 64) ^ xr) >> 1];
            oacc[dt] = __builtin_amdgcn_mfma_f32_16x16x32_bf16(pa0, vb0, oacc[dt], 0, 0, 0);
            oacc[dt] = __builtin_amdgcn_mfma_f32_16x16x32_bf16(pa1, vb1, oacc[dt], 0, 0, 0);
        }
        __syncthreads();   // next tile staged (vmcnt 0) + all waves done with buf[t]
    }

    float inv[4];
    for (int r = 0; r < 4; ++r) {
        float lsum = lpart[r];
        for (int x = 1; x < 16; x <<= 1) lsum += __shfl_xor(lsum, x);
        inv[r] = 1.0f / lsum;
    }
    for (int dt = 0; dt < 8; ++dt)
        for (int r = 0; r < 4; ++r) {
            int qg = qbase + g * 4 + r;
            Oa[(size_t)qg * (NHEAD * HDIM) + h * HDIM + dt * 16 + fr] =
                __float2bfloat16(oacc[dt][r] * inv[r]);
        }
}

// ---------------------------------------------------------------- launch
extern "C" void kernel_launch(void* const* d_in, const int* in_sizes, int n_in,
                              void* d_out, int out_size, void* d_ws, size_t ws_size,
                              hipStream_t stream) {
    const float* hs   = (const float*)d_in[0];
    const float* cosp = (const float*)d_in[1];
    const float* sinp = (const float*)d_in[2];
    const float* wq   = (const float*)d_in[3];
    const float* wk   = (const float*)d_in[4];
    const float* wv   = (const float*)d_in[5];
    const float* wo   = (const float*)d_in[6];
    const float* qnw  = (const float*)d_in[7];
    const float* knw  = (const float*)d_in[8];
    float* out = (float*)d_out;
    char* ws = (char*)d_ws;

    // workspace timeline (max 68 MB):
    // phase1 prep:  hsb[0,8.4M) WqkvT[8.4M,29.4M)
    // phase2 gemm1: + P0 bf16 [29.4M,50.3M) P1 bf16 [50.3M,71.3M)
    // phase3 pack:  Qh[8.4M,25.2M) Kh[25.2M,27.3M) Vt[27.3M,29.4M)  (over dead WqkvT)
    // phase4 woT:   WoT[50.3M,67.1M)                                (over dead P1)
    // phase5 attn:  Oa[33.6M,50.3M)                                 (over dead P0)
    // phase6 gemm2: Qa0[0,16.8M) Qa1[16.8M,33.6M)                   (over dead hsb/Qh/Kh/Vt)
    __hip_bfloat16* hsb    = (__hip_bfloat16*)(ws);
    __hip_bfloat16* WqkvT  = (__hip_bfloat16*)(ws + 8388608);
    __hip_bfloat16* P0     = (__hip_bfloat16*)(ws + 29360128);
    __hip_bfloat16* P1     = (__hip_bfloat16*)(ws + 50331648);
    __hip_bfloat16* Qh     = (__hip_bfloat16*)(ws + 8388608);
    __hip_bfloat16* Kh     = (__hip_bfloat16*)(ws + 25165824);
    __hip_bfloat16* Vt     = (__hip_bfloat16*)(ws + 27262976);
    __hip_bfloat16* WoT    = (__hip_bfloat16*)(ws + 50331648);
    __hip_bfloat16* Oa     = (__hip_bfloat16*)(ws + 33554432);
    float*          Qa0    = (float*)(ws);
    float*          Qa1    = (float*)(ws + 16777216);

    prep_kernel<<<14336, 256, 0, stream>>>(hs, hsb, wq, wk, wv, WqkvT);
    // QKV projection, split-K=2, bf16 partials (czstride = 20971520 B / 2 = 10485760 elems)
    gemm_bt_kernel<__hip_bfloat16><<<dim3(40, 16, 2), 256, 0, stream>>>(
        hsb, WqkvT, P0, 2048, 5120, 1024, 2048, 1024, 10485760LL);
    pack_kernel<<<dim3(2048, 10), 256, 0, stream>>>(P0, P1, cosp, sinp, qnw, knw, Qh, Kh, Vt);
    transpose_cast_kernel<<<dim3(64, 128), 256, 0, stream>>>(wo, WoT, 4096, 2048);
    attn_kernel<<<dim3(512), 512, 0, stream>>>(Qh, Kh, Vt, Oa);
    // O-projection: split-K=2 fp32 partials (czstride = 16777216 B / 4 = 4194304 elems)
    gemm_bt_kernel<float><<<dim3(16, 16, 2), 256, 0, stream>>>(
        Oa, WoT, Qa0, 2048, 2048, 2048, 4096, 2048, 4194304LL);
    add2_kernel<<<4096, 256, 0, stream>>>(Qa0, Qa1, out, (2048 * 2048) / 4);
}

// Round 7
// 244.959 us; speedup vs baseline: 2.7692x; 1.0681x over previous
//
#include <hip/hip_runtime.h>
#include <hip/hip_bf16.h>

using short4v = __attribute__((ext_vector_type(4))) short;
using short8 = __attribute__((ext_vector_type(8))) short;
using f32x4  = __attribute__((ext_vector_type(4))) float;

#define SEQ 2048
#define NHEAD 32
#define NKVH 4
#define HDIM 128
// 1/sqrt(128) * log2(e)  -- exp2-domain softmax, folded into Q at pack time
#define QK_SCALE_LOG2 (0.08838834764831845f * 1.44269504088896340f)

__device__ __forceinline__ float fast_exp2(float x) { return __builtin_amdgcn_exp2f(x); }
__device__ __forceinline__ float b2f(short u) {
    return __uint_as_float(((unsigned)(unsigned short)u) << 16);
}
__device__ __forceinline__ short f2bb(float f) {
    __hip_bfloat16 h = __float2bfloat16(f);
    return *reinterpret_cast<short*>(&h);
}

// ---------------------------------------------------------------- fused prep: cast hs + transpose wq/wk/wv/wo
// [0,4096): cast hs (2048x2048 fp32 -> bf16)
// [4096,12288): wq (2048,4096) -> WqkvT rows 0..4095
// [12288,13312): wk -> WqkvT rows 4096..4607
// [13312,14336): wv -> WqkvT rows 4608..5119
// [14336,22528): wo (4096,2048) -> WoT (2048,4096)
__global__ __launch_bounds__(256) void prep_kernel(
    const float* __restrict__ hs, __hip_bfloat16* __restrict__ hsb,
    const float* __restrict__ wq, const float* __restrict__ wk, const float* __restrict__ wv,
    const float* __restrict__ wo,
    __hip_bfloat16* __restrict__ WqkvT, __hip_bfloat16* __restrict__ WoT) {
    const int b = blockIdx.x, tid = threadIdx.x;
    if (b < 4096) {
        int i = b * 256 + tid;
        float4 v = ((const float4*)hs)[i];
        __hip_bfloat16 h4[4] = {__float2bfloat16(v.x), __float2bfloat16(v.y),
                                __float2bfloat16(v.z), __float2bfloat16(v.w)};
        ((ushort4*)hsb)[i] = *(ushort4*)h4;
        return;
    }
    __shared__ float tile[32][33];
    const float* W; __hip_bfloat16* Wt; int N, ld, nb, kb;
    if (b < 12288)      { int bb = b - 4096;  W = wq; Wt = WqkvT;                       N = 4096; ld = 2048; nb = (bb & 127) * 32; kb = (bb >> 7) * 32; }
    else if (b < 13312) { int bb = b - 12288; W = wk; Wt = WqkvT + (size_t)4096 * 2048; N = 512;  ld = 2048; nb = (bb & 15) * 32;  kb = (bb >> 4) * 32; }
    else if (b < 14336) { int bb = b - 13312; W = wv; Wt = WqkvT + (size_t)4608 * 2048; N = 512;  ld = 2048; nb = (bb & 15) * 32;  kb = (bb >> 4) * 32; }
    else                { int bb = b - 14336; W = wo; Wt = WoT;                         N = 2048; ld = 4096; nb = (bb & 63) * 32;  kb = (bb >> 6) * 32; }
    int tx = tid & 31, ty = tid >> 5;   // 32 x 8
    for (int j = 0; j < 32; j += 8)
        tile[ty + j][tx] = W[(size_t)(kb + ty + j) * N + nb + tx];
    __syncthreads();
    for (int j = 0; j < 32; j += 8)
        Wt[(size_t)(nb + ty + j) * ld + kb + tx] = __float2bfloat16(tile[tx][ty + j]);
}

// ---------------------------------------------------------------- bf16 partial add -> fp32 out
__global__ void add2b_kernel(const __hip_bfloat16* __restrict__ a, const __hip_bfloat16* __restrict__ b,
                             float* __restrict__ o, int n4) {
    int i = blockIdx.x * blockDim.x + threadIdx.x;
    if (i >= n4) return;
    short4v x = ((const short4v*)a)[i];
    short4v y = ((const short4v*)b)[i];
    float4 z = {b2f(x[0]) + b2f(y[0]), b2f(x[1]) + b2f(y[1]),
                b2f(x[2]) + b2f(y[2]), b2f(x[3]) + b2f(y[3])};
    ((float4*)o)[i] = z;
}

// ---------------------------------------------------------------- GEMM: A(M,*)bf16 x Bt(N,*)bf16 -> C(M,N)
#define BM 128
#define BN 128
#define BKK 32
template <typename OutT>
__global__ __launch_bounds__(256) void gemm_bt_kernel(
    const __hip_bfloat16* __restrict__ A, const __hip_bfloat16* __restrict__ Bt,
    OutT* __restrict__ C, int M, int N, int Kext, int ld, int koff, long long czstride) {
    A  += (size_t)blockIdx.z * koff;
    Bt += (size_t)blockIdx.z * koff;
    C  += (size_t)blockIdx.z * czstride;
    __shared__ __align__(16) __hip_bfloat16 sA[BM * BKK];
    __shared__ __align__(16) __hip_bfloat16 sB[BN * BKK];
    const int tid = threadIdx.x;
    const int w = tid >> 6, l = tid & 63;
    const int wr = w >> 1, wc = w & 1;
    const int row0 = blockIdx.y * BM;
    const int col0 = blockIdx.x * BN;
    const int srow = l >> 2;          // 0..15
    const int scol = (l & 3) * 8;     // 0,8,16,24

    f32x4 acc[4][4] = {};
    const int fr = l & 15;
    const int fc = (l >> 4) * 8;

    for (int k0 = 0; k0 < Kext; k0 += BKK) {
        for (int i = 0; i < 2; ++i) {
            int c = i * 4 + w;  // chunk 0..7, 16 rows each
            const __hip_bfloat16* ga = A + (size_t)(row0 + c * 16 + srow) * ld + k0 + scol;
            __builtin_amdgcn_global_load_lds((const __attribute__((address_space(1))) void*)ga,
                                             (__attribute__((address_space(3))) void*)&sA[c * 16 * BKK], 16, 0, 0);
            const __hip_bfloat16* gb = Bt + (size_t)(col0 + c * 16 + srow) * ld + k0 + scol;
            __builtin_amdgcn_global_load_lds((const __attribute__((address_space(1))) void*)gb,
                                             (__attribute__((address_space(3))) void*)&sB[c * 16 * BKK], 16, 0, 0);
        }
        __syncthreads();
        short8 af[4], bfr[4];
        for (int m = 0; m < 4; ++m)
            af[m] = *(const short8*)&sA[(wr * 64 + m * 16 + fr) * BKK + fc];
        for (int n = 0; n < 4; ++n)
            bfr[n] = *(const short8*)&sB[(wc * 64 + n * 16 + fr) * BKK + fc];
        for (int m = 0; m < 4; ++m)
            for (int n = 0; n < 4; ++n)
                acc[m][n] = __builtin_amdgcn_mfma_f32_16x16x32_bf16(af[m], bfr[n], acc[m][n], 0, 0, 0);
        __syncthreads();
    }
    const int fq = l >> 4;
    for (int m = 0; m < 4; ++m)
        for (int n = 0; n < 4; ++n)
            for (int r = 0; r < 4; ++r) {
                int row = row0 + wr * 64 + m * 16 + fq * 4 + r;
                int col = col0 + wc * 64 + n * 16 + fr;
                float v = acc[m][n][r];
                if constexpr (__is_same(OutT, float)) C[(size_t)row * N + col] = v;
                else C[(size_t)row * N + col] = __float2bfloat16(v);
            }
}

// ---------------------------------------------------------------- fused partial-add + RMSNorm + RoPE + pack (vectorized)
// grid (1024, 5), 256 thr: 16 rows/block, 16 lanes/row, 4+4 elems/lane.
__global__ __launch_bounds__(256) void pack_kernel(
    const __hip_bfloat16* __restrict__ P0, const __hip_bfloat16* __restrict__ P1,
    const float* __restrict__ cosp, const float* __restrict__ sinp,
    const float* __restrict__ qnw, const float* __restrict__ knw,
    __hip_bfloat16* __restrict__ Qh, __hip_bfloat16* __restrict__ Kh, __hip_bfloat16* __restrict__ Vt) {
    const int tid = threadIdx.x;
    const int rloc = tid >> 4, l16 = tid & 15;
    const int r = blockIdx.y * 16 + rloc;          // 0..79
    const int s = blockIdx.x * 2 + (r >= 40 ? 1 : 0);
    const int slot = (r >= 40) ? r - 40 : r;
    int off;
    if (slot < 32)      off = slot * 128;
    else if (slot < 36) off = 4096 + (slot - 32) * 128;
    else                off = 4608 + (slot - 36) * 128;
    const int d0 = l16 * 4;
    const size_t base = (size_t)s * 5120 + off;

    short4v a0 = *(const short4v*)&P0[base + d0];
    short4v a1 = *(const short4v*)&P0[base + d0 + 64];
    short4v b0 = *(const short4v*)&P1[base + d0];
    short4v b1 = *(const short4v*)&P1[base + d0 + 64];
    float x1[4], x2[4];
    for (int j = 0; j < 4; ++j) {
        x1[j] = b2f(a0[j]) + b2f(b0[j]);
        x2[j] = b2f(a1[j]) + b2f(b1[j]);
    }

    if (slot >= 36) {   // V: cast + transpose to (D,S)
        int t = slot - 36;
        for (int j = 0; j < 4; ++j) {
            Vt[((size_t)t * 128 + d0 + j) * SEQ + s]      = __float2bfloat16(x1[j]);
            Vt[((size_t)t * 128 + d0 + 64 + j) * SEQ + s] = __float2bfloat16(x2[j]);
        }
        return;
    }
    float ss = 0.f;
    for (int j = 0; j < 4; ++j) ss += x1[j] * x1[j] + x2[j] * x2[j];
    for (int x = 1; x < 16; x <<= 1) ss += __shfl_xor(ss, x);
    float rs = rsqrtf(ss * (1.0f / 128.0f) + 1e-6f);

    f32x4 c4 = *(const f32x4*)&cosp[(size_t)s * 128 + d0];   // cos[d]==cos[d+64]
    f32x4 s4 = *(const f32x4*)&sinp[(size_t)s * 128 + d0];
    const float* wgt = (slot < 32) ? qnw : knw;
    f32x4 w1 = *(const f32x4*)&wgt[d0];
    f32x4 w2 = *(const f32x4*)&wgt[d0 + 64];
    const float scl = (slot < 32) ? QK_SCALE_LOG2 : 1.0f;

    short4v o1, o2;
    for (int j = 0; j < 4; ++j) {
        float a = x1[j] * rs * w1[j], b = x2[j] * rs * w2[j];
        o1[j] = f2bb((a * c4[j] - b * s4[j]) * scl);
        o2[j] = f2bb((b * c4[j] + a * s4[j]) * scl);
    }
    __hip_bfloat16* dst;
    if (slot < 32) dst = Qh + ((size_t)slot * SEQ + s) * 128;
    else           dst = Kh + ((size_t)(slot - 32) * SEQ + s) * 128;
    *(short4v*)&dst[d0]      = o1;
    *(short4v*)&dst[d0 + 64] = o2;
}

// ---------------------------------------------------------------- causal GQA flash attention (R5 structure + setprio)
// 4 waves/block = 4 q-heads of one kv-group half, same 16-row q-range.
// K/V tiles (KVBLK=64) double-buffered via global_load_lds, XOR-swizzle byte^=(row&7)<<4.
__global__ __launch_bounds__(256, 2) void attn_kernel(
    const __hip_bfloat16* __restrict__ Qh,  // [NH][S][D], scale*log2e folded
    const __hip_bfloat16* __restrict__ Kh,  // [NKV][S][D]
    const __hip_bfloat16* __restrict__ Vt,  // [NKV][D][S]
    __hip_bfloat16* __restrict__ Oa) {      // [S][NH*D]
    __shared__ __align__(16) __hip_bfloat16 sK[2][64 * 128];   // 2 x 16 KB
    __shared__ __align__(16) __hip_bfloat16 sV[2][128 * 64];   // 2 x 16 KB
    __shared__ __align__(16) __hip_bfloat16 sP[4][16 * 72];    // per-wave P

    const int tid = threadIdx.x;
    const int w = tid >> 6, l = tid & 63;
    const int bx = blockIdx.x;
    const int y = bx & 7;                      // kv-slice -> XCD (wgid%8)
    const int qt = 127 - (bx >> 3);            // longest work first
    const int qbase = qt * 16;
    const int hkv = y >> 1;
    const int h = y * 4 + w;                   // this wave's q-head
    const int fr = l & 15, g = l >> 4;

    const __hip_bfloat16* Qp = Qh + ((size_t)h * SEQ + qbase) * HDIM;
    const __hip_bfloat16* Kp = Kh + (size_t)hkv * SEQ * HDIM;
    const __hip_bfloat16* Vp = Vt + (size_t)hkv * HDIM * SEQ;
    __hip_bfloat16* myP = &sP[w][0];

    short8 qf[4];
    for (int c = 0; c < 4; ++c)
        qf[c] = *(const short8*)&Qp[fr * HDIM + c * 32 + g * 8];

    f32x4 oacc[8] = {};
    float mrow[4], lpart[4];
    for (int r = 0; r < 4; ++r) { mrow[r] = -3.0e38f; lpart[r] = 0.f; }

    const int xr = (fr & 7) << 4;              // XOR-swizzle byte offset (read side)
    const int ntiles = ((qbase + 15) >> 6) + 1;

    auto stage = [&](int buf, int kbase) {
        for (int i = 0; i < 4; ++i) {
            int blk = i * 4 + w;               // 0..15, uniform per wave
            {   // K: row = blk*4 + (l>>4)
                int row = blk * 4 + (l >> 4);
                int cb = ((l & 15) * 16) ^ ((row & 7) << 4);
                const __hip_bfloat16* src = Kp + (size_t)(kbase + row) * HDIM + (cb >> 1);
                __builtin_amdgcn_global_load_lds((const __attribute__((address_space(1))) void*)src,
                    (__attribute__((address_space(3))) void*)&sK[buf][blk * 512], 16, 0, 0);
            }
            {   // V: row(d) = blk*8 + (l>>3)
                int row = blk * 8 + (l >> 3);
                int cb = ((l & 7) * 16) ^ ((row & 7) << 4);
                const __hip_bfloat16* src = Vp + (size_t)row * SEQ + kbase + (cb >> 1);
                __builtin_amdgcn_global_load_lds((const __attribute__((address_space(1))) void*)src,
                    (__attribute__((address_space(3))) void*)&sV[buf][blk * 512], 16, 0, 0);
            }
        }
    };

    stage(0, 0);
    __syncthreads();                            // drains vmcnt(0): tile 0 ready

    for (int t = 0; t < ntiles; ++t) {
        const int kbase = t * 64;
        const int buf = t & 1;
        if (t + 1 < ntiles) stage(buf ^ 1, kbase + 64);   // overlap with compute

        // ---- QK^T: 16 q x 64 k from swizzled LDS
        f32x4 s[4] = {};
        __builtin_amdgcn_s_setprio(1);
        for (int j = 0; j < 4; ++j) {
            const __hip_bfloat16* kp = &sK[buf][(j * 16 + fr) * 128];
            for (int c = 0; c < 4; ++c) {
                short8 kf = *(const short8*)&kp[((c * 64 + g * 16) ^ xr) >> 1];
                s[j] = __builtin_amdgcn_mfma_f32_16x16x32_bf16(qf[c], kf, s[j], 0, 0, 0);
            }
        }
        __builtin_amdgcn_s_setprio(0);
        // ---- online softmax (exp2 domain), causal mask, defer-max THR=12
        float v[4][4], mloc[4];
        const bool full = (kbase + 63 <= qbase);   // wave-uniform: no masking needed
        for (int r = 0; r < 4; ++r) {
            if (full) {
                v[r][0] = s[0][r]; v[r][1] = s[1][r]; v[r][2] = s[2][r]; v[r][3] = s[3][r];
            } else {
                const int qg = qbase + g * 4 + r;
                v[r][0] = (kbase + fr      <= qg) ? s[0][r] : -1e30f;
                v[r][1] = (kbase + 16 + fr <= qg) ? s[1][r] : -1e30f;
                v[r][2] = (kbase + 32 + fr <= qg) ? s[2][r] : -1e30f;
                v[r][3] = (kbase + 48 + fr <= qg) ? s[3][r] : -1e30f;
            }
            float m = fmaxf(fmaxf(v[r][0], v[r][1]), fmaxf(v[r][2], v[r][3]));
            for (int x = 1; x < 16; x <<= 1) m = fmaxf(m, __shfl_xor(m, x));
            mloc[r] = m;
        }
        int grow = (mloc[0] > mrow[0] + 12.0f) | (mloc[1] > mrow[1] + 12.0f) |
                   (mloc[2] > mrow[2] + 12.0f) | (mloc[3] > mrow[3] + 12.0f);
        if (__any(grow)) {
            for (int r = 0; r < 4; ++r) {
                float mnew = fmaxf(mrow[r], mloc[r]);
                float corr = fast_exp2(mrow[r] - mnew);
                mrow[r] = mnew;
                lpart[r] *= corr;
                for (int dt = 0; dt < 8; ++dt) oacc[dt][r] *= corr;
            }
        }
        for (int r = 0; r < 4; ++r) {
            float e0 = fast_exp2(v[r][0] - mrow[r]);
            float e1 = fast_exp2(v[r][1] - mrow[r]);
            float e2 = fast_exp2(v[r][2] - mrow[r]);
            float e3 = fast_exp2(v[r][3] - mrow[r]);
            lpart[r] += (e0 + e1) + (e2 + e3);
            const int prow = (g * 4 + r) * 72;
            myP[prow + fr]      = __float2bfloat16(e0);
            myP[prow + 16 + fr] = __float2bfloat16(e1);
            myP[prow + 32 + fr] = __float2bfloat16(e2);
            myP[prow + 48 + fr] = __float2bfloat16(e3);
        }
        // ---- PV: P(16x64) x V^T(64xD) from swizzled LDS
        short8 pa0 = *(const short8*)&myP[fr * 72 + g * 8];
        short8 pa1 = *(const short8*)&myP[fr * 72 + 32 + g * 8];
        __builtin_amdgcn_s_setprio(1);
        for (int dt = 0; dt < 8; ++dt) {
            const __hip_bfloat16* vp = &sV[buf][(dt * 16 + fr) * 64];
            short8 vb0 = *(const short8*)&vp[((g * 16)      ^ xr) >> 1];
            short8 vb1 = *(const short8*)&vp[((g * 16 + 64) ^ xr) >> 1];
            oacc[dt] = __builtin_amdgcn_mfma_f32_16x16x32_bf16(pa0, vb0, oacc[dt], 0, 0, 0);
            oacc[dt] = __builtin_amdgcn_mfma_f32_16x16x32_bf16(pa1, vb1, oacc[dt], 0, 0, 0);
        }
        __builtin_amdgcn_s_setprio(0);
        __syncthreads();   // next tile staged (vmcnt 0) + all waves done with buf[t]
    }

    float inv[4];
    for (int r = 0; r < 4; ++r) {
        float lsum = lpart[r];
        for (int x = 1; x < 16; x <<= 1) lsum += __shfl_xor(lsum, x);
        inv[r] = 1.0f / lsum;
    }
    for (int dt = 0; dt < 8; ++dt)
        for (int r = 0; r < 4; ++r) {
            int qg = qbase + g * 4 + r;
            Oa[(size_t)qg * (NHEAD * HDIM) + h * HDIM + dt * 16 + fr] =
                __float2bfloat16(oacc[dt][r] * inv[r]);
        }
}

// ---------------------------------------------------------------- launch
extern "C" void kernel_launch(void* const* d_in, const int* in_sizes, int n_in,
                              void* d_out, int out_size, void* d_ws, size_t ws_size,
                              hipStream_t stream) {
    const float* hs   = (const float*)d_in[0];
    const float* cosp = (const float*)d_in[1];
    const float* sinp = (const float*)d_in[2];
    const float* wq   = (const float*)d_in[3];
    const float* wk   = (const float*)d_in[4];
    const float* wv   = (const float*)d_in[5];
    const float* wo   = (const float*)d_in[6];
    const float* qnw  = (const float*)d_in[7];
    const float* knw  = (const float*)d_in[8];
    float* out = (float*)d_out;
    char* ws = (char*)d_ws;

    // workspace timeline (exactly 88,080,384 B):
    // phase1 prep:  hsb[0,8.39M) WqkvT[8.39M,29.36M) WoT[29.36M,46.14M)
    // phase2 gemm1: P0[46.14M,67.11M) P1[67.11M,88.08M)  (bf16, split-K=2)
    // phase3 pack:  Qh[8.39M,25.17M) Kh[25.17M,27.26M) Vt[27.26M,29.36M)  (over dead WqkvT)
    // phase4 attn:  Oa[46.14M,62.91M)                                     (over dead P0)
    // phase5 gemm2: Qb0[67.11M,75.50M) Qb1[75.50M,83.89M)                 (over dead P1)
    __hip_bfloat16* hsb    = (__hip_bfloat16*)(ws);
    __hip_bfloat16* WqkvT  = (__hip_bfloat16*)(ws + 8388608);
    __hip_bfloat16* WoT    = (__hip_bfloat16*)(ws + 29360128);
    __hip_bfloat16* P0     = (__hip_bfloat16*)(ws + 46137344);
    __hip_bfloat16* P1     = (__hip_bfloat16*)(ws + 67108864);
    __hip_bfloat16* Qh     = (__hip_bfloat16*)(ws + 8388608);
    __hip_bfloat16* Kh     = (__hip_bfloat16*)(ws + 25165824);
    __hip_bfloat16* Vt     = (__hip_bfloat16*)(ws + 27262976);
    __hip_bfloat16* Oa     = (__hip_bfloat16*)(ws + 46137344);
    __hip_bfloat16* Qb0    = (__hip_bfloat16*)(ws + 67108864);
    __hip_bfloat16* Qb1    = (__hip_bfloat16*)(ws + 75497472);

    prep_kernel<<<22528, 256, 0, stream>>>(hs, hsb, wq, wk, wv, wo, WqkvT, WoT);
    // QKV projection, split-K=2, bf16 partials (czstride = 20,971,520 B / 2 = 10,485,760 elems)
    gemm_bt_kernel<__hip_bfloat16><<<dim3(40, 16, 2), 256, 0, stream>>>(
        hsb, WqkvT, P0, 2048, 5120, 1024, 2048, 1024, 10485760LL);
    pack_kernel<<<dim3(1024, 5), 256, 0, stream>>>(P0, P1, cosp, sinp, qnw, knw, Qh, Kh, Vt);
    attn_kernel<<<dim3(1024), 256, 0, stream>>>(Qh, Kh, Vt, Oa);
    // O-projection: split-K=2, bf16 partials (czstride = 8,388,608 B / 2 = 4,194,304 elems)
    gemm_bt_kernel<__hip_bfloat16><<<dim3(16, 16, 2), 256, 0, stream>>>(
        Oa, WoT, Qb0, 2048, 2048, 2048, 4096, 2048, 4194304LL);
    add2b_kernel<<<4096, 256, 0, stream>>>(Qb0, Qb1, out, (2048 * 2048) / 4);
}